// Round 1
// baseline (1323.183 us; speedup 1.0000x reference)
//
#include <hip/hip_runtime.h>
#include <math.h>

#define S_LEN 4096
#define HIDN  1024
#define NH    16
#define HD    64
#define BATCH 2
#define M_TOTAL (BATCH * S_LEN)   // 8192
#define N_RKV   (3 * HIDN)        // 3072
#define CS 128
#define NC (S_LEN / CS)           // 32

// ---------- K0: a = mean(exp(time_decay))  (note: a = -avg_decay > 0) ----------
__global__ void k_avg_decay(const float* __restrict__ td, float* __restrict__ a_out) {
    int t = threadIdx.x;
    double acc = 0.0;
    for (int i = t; i < NH * HD; i += 64) acc += exp((double)td[i]);
    for (int off = 32; off > 0; off >>= 1) acc += __shfl_down(acc, off, 64);
    if (t == 0) a_out[0] = (float)(acc / (double)(NH * HD));
}

// ---------- Tiled fp32 GEMM: C[m][n] = sum_k A[m][k] * W[n][k] ----------
// BM=BN=128, BK=16, 256 threads, 8x8 microtile.
// FUSE_MIX: A[m][k] = hs[m][k]*tm[k] + hs[m-1][k]*(1-tm[k])  (0 at seq start)
template<bool FUSE_MIX>
__global__ __launch_bounds__(256)
void k_gemm(const float* __restrict__ A, int lda,
            const float* __restrict__ hs, const float* __restrict__ tm,
            const float* __restrict__ W, int ldb,
            float* __restrict__ Cmat, int ldc)
{
    const int K = 1024;
    __shared__ float As[16][128 + 4];
    __shared__ float Bs[16][128 + 4];
    const int tid = threadIdx.x;
    const int tx = tid & 15, ty = tid >> 4;
    const int m0 = blockIdx.y * 128;
    const int n0 = blockIdx.x * 128;

    float acc[8][8];
#pragma unroll
    for (int i = 0; i < 8; ++i)
#pragma unroll
        for (int j = 0; j < 8; ++j) acc[i][j] = 0.f;

    for (int kt = 0; kt < K; kt += 16) {
        // stage A tile (transposed into As[k][m])
#pragma unroll
        for (int i = 0; i < 2; ++i) {
            int idx = tid + i * 256;          // 0..511 over (m,k4)
            int ml = idx >> 2;
            int k4 = (idx & 3) * 4;
            int gm = m0 + ml;
            int gk = kt + k4;
            float4 val;
            if (FUSE_MIX) {
                float4 cur = *(const float4*)&hs[(size_t)gm * HIDN + gk];
                float4 t4  = *(const float4*)&tm[gk];
                float4 prev = make_float4(0.f, 0.f, 0.f, 0.f);
                if (gm & (S_LEN - 1)) prev = *(const float4*)&hs[(size_t)(gm - 1) * HIDN + gk];
                val.x = cur.x * t4.x + prev.x * (1.f - t4.x);
                val.y = cur.y * t4.y + prev.y * (1.f - t4.y);
                val.z = cur.z * t4.z + prev.z * (1.f - t4.z);
                val.w = cur.w * t4.w + prev.w * (1.f - t4.w);
            } else {
                val = *(const float4*)&A[(size_t)gm * lda + gk];
            }
            As[k4 + 0][ml] = val.x;
            As[k4 + 1][ml] = val.y;
            As[k4 + 2][ml] = val.z;
            As[k4 + 3][ml] = val.w;
        }
        // stage B tile (W row-major [n][k] -> Bs[k][n])
#pragma unroll
        for (int i = 0; i < 2; ++i) {
            int idx = tid + i * 256;
            int nl = idx >> 2;
            int k4 = (idx & 3) * 4;
            float4 v = *(const float4*)&W[(size_t)(n0 + nl) * ldb + kt + k4];
            Bs[k4 + 0][nl] = v.x;
            Bs[k4 + 1][nl] = v.y;
            Bs[k4 + 2][nl] = v.z;
            Bs[k4 + 3][nl] = v.w;
        }
        __syncthreads();
#pragma unroll
        for (int kk = 0; kk < 16; ++kk) {
            float4 a0 = *(float4*)&As[kk][ty * 8];
            float4 a1 = *(float4*)&As[kk][ty * 8 + 4];
            float4 b0 = *(float4*)&Bs[kk][tx * 8];
            float4 b1 = *(float4*)&Bs[kk][tx * 8 + 4];
            float av[8] = {a0.x, a0.y, a0.z, a0.w, a1.x, a1.y, a1.z, a1.w};
            float bv[8] = {b0.x, b0.y, b0.z, b0.w, b1.x, b1.y, b1.z, b1.w};
#pragma unroll
            for (int i = 0; i < 8; ++i)
#pragma unroll
                for (int j = 0; j < 8; ++j) acc[i][j] += av[i] * bv[j];
        }
        __syncthreads();
    }

#pragma unroll
    for (int i = 0; i < 8; ++i) {
        int row = m0 + ty * 8 + i;
        float4 o0 = make_float4(acc[i][0], acc[i][1], acc[i][2], acc[i][3]);
        float4 o1 = make_float4(acc[i][4], acc[i][5], acc[i][6], acc[i][7]);
        *(float4*)&Cmat[(size_t)row * ldc + n0 + tx * 8]     = o0;
        *(float4*)&Cmat[(size_t)row * ldc + n0 + tx * 8 + 4] = o1;
    }
}

// ---------- K3: sigmoid(r), RoPE(r,k), kv = k*v   (in place in rkv buffer) ----------
// Each thread owns pair (d, d+32) of one (m,h): no cross-thread hazards.
__global__ __launch_bounds__(256)
void k_rope(float* __restrict__ rkv, const float* __restrict__ cosp, const float* __restrict__ sinp) {
    int g = blockIdx.x * 256 + threadIdx.x;   // over B*S*H*32
    int d = g & 31;
    int h = (g >> 5) & 15;
    int m = g >> 9;
    int s = m & (S_LEN - 1);
    size_t base = (size_t)m * N_RKV + h * HD + d;
    float r0 = rkv[base],        r1 = rkv[base + 32];
    float k0 = rkv[base + 1024], k1 = rkv[base + 1056];
    float v0 = rkv[base + 2048], v1 = rkv[base + 2080];
    float c0  = cosp[s * HD + d], c1  = cosp[s * HD + d + 32];
    float sn0 = sinp[s * HD + d], sn1 = sinp[s * HD + d + 32];
    r0 = 1.f / (1.f + expf(-r0));
    r1 = 1.f / (1.f + expf(-r1));
    float rr0 = r0 * c0 - r1 * sn0;   // rotate_half: [-x2, x1]
    float rr1 = r1 * c1 + r0 * sn1;
    float kk0 = k0 * c0 - k1 * sn0;
    float kk1 = k1 * c1 + k0 * sn1;
    rkv[base]        = rr0;
    rkv[base + 32]   = rr1;
    rkv[base + 1024] = kk0 * v0;  // kv
    rkv[base + 1056] = kk1 * v1;
}

// ---------- K4: per-chunk weighted sums  G[bh,c,d] = sum_j exp(a*j_local)*kv ----------
__global__ __launch_bounds__(64)
void k_chunk_sums(const float* __restrict__ rkv, const float* __restrict__ a_ptr,
                  float* __restrict__ Cb) {
    int bid = blockIdx.x;            // bh*NC + c
    int c  = bid & (NC - 1);
    int bh = bid >> 5;
    int b = bh >> 4, h = bh & 15;
    int d = threadIdx.x;
    float a = a_ptr[0];
    float acc = 0.f;
    const float* p = rkv + (size_t)(b * S_LEN + c * CS) * N_RKV + 1024 + h * HD + d;
    for (int j = 0; j < CS; ++j) {
        acc += expf(a * (float)j) * (*p);
        p += N_RKV;
    }
    Cb[(size_t)bid * 64 + d] = acc;
}

// ---------- K5: exclusive chunk suffix: Sn[c] = G[c+1] + e^{a*CS} * Sn[c+1] ----------
__global__ __launch_bounds__(64)
void k_chunk_suffix(const float* __restrict__ Cb, const float* __restrict__ a_ptr,
                    float* __restrict__ Sb) {
    int bh = blockIdx.x;
    int d = threadIdx.x;
    float a = a_ptr[0];
    float eaCS = expf(a * (float)CS);
    float run = 0.f;
    Sb[(size_t)(bh * NC + NC - 1) * 64 + d] = 0.f;
    for (int c = NC - 2; c >= 0; --c) {
        run = Cb[(size_t)(bh * NC + c + 1) * 64 + d] + eaCS * run;
        Sb[(size_t)(bh * NC + c) * 64 + d] = run;
    }
}

// ---------- K6: in-chunk suffix scan + epilogue out = r'*(tf*kv + S/Z) ----------
__global__ __launch_bounds__(64)
void k_wkv(float* __restrict__ rkv, const float* __restrict__ Sb,
           const float* __restrict__ a_ptr, const float* __restrict__ tf) {
    int bid = blockIdx.x;            // bh*NC + c
    int c  = bid & (NC - 1);
    int bh = bid >> 5;
    int b = bh >> 4, h = bh & 15;
    int d = threadIdx.x;
    float a = a_ptr[0];
    float ea = expf(a);
    float em1a = expm1f(a);
    float S_run = Sb[(size_t)bid * 64 + d];
    float tfv = tf[h * HD + d];
    for (int i = CS - 1; i >= 0; --i) {
        int ig = c * CS + i;
        size_t rowbase = (size_t)(b * S_LEN + ig) * N_RKV + h * HD + d;
        float kv = rkv[rowbase + 1024];
        S_run = kv + ea * S_run;                       // S_i = kv_i + e^a * S_{i+1}
        float Z = expm1f(a * (float)(S_LEN - ig)) / em1a + 1e-8f;
        float wkv = S_run / Z;
        float rr = rkv[rowbase];
        rkv[rowbase + 2048] = rr * (tfv * kv + wkv);   // reuse v-slot for 'out'
    }
}

extern "C" void kernel_launch(void* const* d_in, const int* in_sizes, int n_in,
                              void* d_out, int out_size, void* d_ws, size_t ws_size,
                              hipStream_t stream) {
    const float* hs    = (const float*)d_in[0];
    const float* cosp  = (const float*)d_in[1];
    const float* sinp  = (const float*)d_in[2];
    const float* W_rkv = (const float*)d_in[3];
    const float* W_o   = (const float*)d_in[4];
    const float* td    = (const float*)d_in[5];
    const float* tf    = (const float*)d_in[6];
    const float* tm    = (const float*)d_in[7];
    float* out = (float*)d_out;

    float* rkv   = (float*)d_ws;                                    // 8192*3072 f32 = 96 MiB
    float* Cb    = rkv + (size_t)M_TOTAL * N_RKV;                   // 1024*64
    float* Sb    = Cb + (size_t)BATCH * NH * NC * 64;               // 1024*64
    float* a_ptr = Sb + (size_t)BATCH * NH * NC * 64;               // 1 f32

    k_avg_decay<<<1, 64, 0, stream>>>(td, a_ptr);

    dim3 g1(N_RKV / 128, M_TOTAL / 128);
    k_gemm<true><<<g1, 256, 0, stream>>>(nullptr, 0, hs, tm, W_rkv, HIDN, rkv, N_RKV);

    k_rope<<<(M_TOTAL * NH * 32) / 256, 256, 0, stream>>>(rkv, cosp, sinp);

    k_chunk_sums<<<BATCH * NH * NC, 64, 0, stream>>>(rkv, a_ptr, Cb);
    k_chunk_suffix<<<BATCH * NH, 64, 0, stream>>>(Cb, a_ptr, Sb);
    k_wkv<<<BATCH * NH * NC, 64, 0, stream>>>(rkv, Sb, a_ptr, tf);

    dim3 g2(HIDN / 128, M_TOTAL / 128);
    k_gemm<false><<<g2, 256, 0, stream>>>(rkv + 2048, N_RKV, nullptr, nullptr, W_o, HIDN, out, HIDN);
}

// Round 3
// 430.199 us; speedup vs baseline: 3.0757x; 3.0757x over previous
//
#include <hip/hip_runtime.h>
#include <math.h>

#define S_LEN 4096
#define HIDN  1024
#define NH    16
#define HD    64
#define BATCH 2
#define M_TOTAL (BATCH * S_LEN)   // 8192
#define N_RKV   (3 * HIDN)        // 3072
#define CS 128
#define NC (S_LEN / CS)           // 32

typedef __attribute__((ext_vector_type(8))) short bf16x8;
typedef __attribute__((ext_vector_type(4))) float f32x4;
typedef __attribute__((ext_vector_type(4))) unsigned short u16x4;

// ---------- bf16 split helpers (manual RNE, bit-exact) ----------
__device__ __forceinline__ unsigned short f2bf_rne(float x) {
    unsigned int u = __float_as_uint(x);
    unsigned int r = (u + 0x7fffu + ((u >> 16) & 1u)) >> 16;
    return (unsigned short)r;
}
__device__ __forceinline__ float bf2f(unsigned short h) {
    return __uint_as_float(((unsigned int)h) << 16);
}
struct BSplit { unsigned short hi, lo; };
__device__ __forceinline__ BSplit bsplit(float x) {
    BSplit r;
    r.hi = f2bf_rne(x);
    r.lo = f2bf_rne(x - bf2f(r.hi));
    return r;
}

// ---------- async global->LDS, 16B per lane, dest = uniform base + lane*16 ----------
__device__ __forceinline__ void load_lds16(const void* g, void* l) {
    __builtin_amdgcn_global_load_lds((const __attribute__((address_space(1))) void*)g,
                                     (__attribute__((address_space(3))) void*)l, 16, 0, 0);
}

// ---------- K0: a = mean(w) = -mean(exp(time_decay)) ----------
__global__ void k_avg_decay(const float* __restrict__ td, float* __restrict__ a_out) {
    int t = threadIdx.x;
    double acc = 0.0;
    for (int i = t; i < NH * HD; i += 64) acc += exp((double)td[i]);
    for (int off = 32; off > 0; off >>= 1) acc += __shfl_down(acc, off, 64);
    if (t == 0) a_out[0] = (float)(acc / (double)(NH * HD));
}

// ---------- K1a: mixed = hs*tm + shift(hs)*(1-tm), split to bf16 hi/lo ----------
__global__ __launch_bounds__(256)
void k_split_mix(const float* __restrict__ hs, const float* __restrict__ tm,
                 unsigned short* __restrict__ Ah, unsigned short* __restrict__ Al) {
    int g = blockIdx.x * 256 + threadIdx.x;      // over M_TOTAL * (HIDN/4)
    int kc = (g & 255) * 4;
    int m = g >> 8;
    float4 cur = *(const float4*)&hs[(size_t)m * HIDN + kc];
    float4 t4  = *(const float4*)&tm[kc];
    float4 prev = make_float4(0.f, 0.f, 0.f, 0.f);
    if (m & (S_LEN - 1)) prev = *(const float4*)&hs[(size_t)(m - 1) * HIDN + kc];
    float x0 = cur.x * t4.x + prev.x * (1.f - t4.x);
    float x1 = cur.y * t4.y + prev.y * (1.f - t4.y);
    float x2 = cur.z * t4.z + prev.z * (1.f - t4.z);
    float x3 = cur.w * t4.w + prev.w * (1.f - t4.w);
    BSplit s0 = bsplit(x0), s1 = bsplit(x1), s2 = bsplit(x2), s3 = bsplit(x3);
    u16x4 h, l;
    h.x = s0.hi; h.y = s1.hi; h.z = s2.hi; h.w = s3.hi;
    l.x = s0.lo; l.y = s1.lo; l.z = s2.lo; l.w = s3.lo;
    size_t o = (size_t)m * HIDN + kc;
    *(u16x4*)&Ah[o] = h;
    *(u16x4*)&Al[o] = l;
}

// ---------- K1b: flat fp32 -> bf16 hi/lo split (weights) ----------
__global__ __launch_bounds__(256)
void k_split_w(const float* __restrict__ W,
               unsigned short* __restrict__ Wh, unsigned short* __restrict__ Wl) {
    int g = blockIdx.x * 256 + threadIdx.x;
    size_t o = (size_t)g * 4;
    float4 v = *(const float4*)&W[o];
    BSplit s0 = bsplit(v.x), s1 = bsplit(v.y), s2 = bsplit(v.z), s3 = bsplit(v.w);
    u16x4 h, l;
    h.x = s0.hi; h.y = s1.hi; h.z = s2.hi; h.w = s3.hi;
    l.x = s0.lo; l.y = s1.lo; l.z = s2.lo; l.w = s3.lo;
    *(u16x4*)&Wh[o] = h;
    *(u16x4*)&Wl[o] = l;
}

// ---------- K2: split-bf16 MFMA GEMM  C[m][n] = sum_k A[m][k] * B[n][k] ----------
// A = Ah+Al, B = Bh+Bl (bf16 hi/lo). 3 MFMA terms: hh + hl + lh.
// 128x128 tile, BK=32, 256 threads (4 waves, 2x2 of 64x64 each).
// LDS: 4 tiles (Ah,Al,Bh,Bl) x 8KB, XOR-swizzled 16B chunks: slot(m,q)=4m+(q^(m&3)).
__global__ __launch_bounds__(256, 2)
void k_mfma_gemm(const unsigned short* __restrict__ Ah, const unsigned short* __restrict__ Al, int lda,
                 const unsigned short* __restrict__ Bh, const unsigned short* __restrict__ Bl, int ldb,
                 float* __restrict__ C, int ldc)
{
    __shared__ unsigned short smem[16384];       // 32 KB
    const int tid  = threadIdx.x;
    const int lane = tid & 63;
    const int wave = tid >> 6;
    const int wm = wave >> 1, wn = wave & 1;
    const int m0 = blockIdx.y * 128;
    const int n0 = blockIdx.x * 128;

    // staging: wave w stages tile w (0=Ah,1=Al,2=Bh,3=Bl), 8 x 1KB segments
    const unsigned short* gsrc;
    int ld;
    {
        int row0 = (wave < 2) ? m0 : n0;
        const unsigned short* base = (wave == 0) ? Ah : (wave == 1) ? Al : (wave == 2) ? Bh : Bl;
        ld = (wave < 2) ? lda : ldb;
        int rowoff = lane >> 2;                       // 0..15 within segment
        int q = (lane & 3) ^ ((lane >> 2) & 3);       // swizzled k-octet
        gsrc = base + (size_t)(row0 + rowoff) * ld + q * 8;
    }
    unsigned short* ldsbase = smem + wave * 4096;     // this wave's tile

    // fragment LDS element offsets (row stride 32 elems, chunk 8 elems)
    const int lm = lane & 15;
    const int qx = (lane >> 4) ^ (lane & 3);          // q' ^ (m&3)
    int aoff[4], boff[4];
#pragma unroll
    for (int t = 0; t < 4; ++t) {
        aoff[t] = (wm * 64 + t * 16 + lm) * 32 + qx * 8;
        boff[t] = 8192 + (wn * 64 + t * 16 + lm) * 32 + qx * 8;
    }

    f32x4 acc[4][4] = {};

    for (int kt = 0; kt < 1024; kt += 32) {
        __syncthreads();                              // previous compute done
        const unsigned short* g = gsrc + kt;
#pragma unroll
        for (int i = 0; i < 8; ++i)
            load_lds16(g + (size_t)i * 16 * ld, ldsbase + i * 512);
        __syncthreads();                              // staging complete

        bf16x8 fah[4], fal[4], fbh[4], fbl[4];
#pragma unroll
        for (int t = 0; t < 4; ++t) {
            fah[t] = *(const bf16x8*)(smem + aoff[t]);
            fal[t] = *(const bf16x8*)(smem + 4096 + aoff[t]);
            fbh[t] = *(const bf16x8*)(smem + boff[t]);
            fbl[t] = *(const bf16x8*)(smem + 4096 + boff[t]);
        }
#pragma unroll
        for (int mt = 0; mt < 4; ++mt)
#pragma unroll
            for (int nt = 0; nt < 4; ++nt) {
                acc[mt][nt] = __builtin_amdgcn_mfma_f32_16x16x32_bf16(fah[mt], fbh[nt], acc[mt][nt], 0, 0, 0);
                acc[mt][nt] = __builtin_amdgcn_mfma_f32_16x16x32_bf16(fah[mt], fbl[nt], acc[mt][nt], 0, 0, 0);
                acc[mt][nt] = __builtin_amdgcn_mfma_f32_16x16x32_bf16(fal[mt], fbh[nt], acc[mt][nt], 0, 0, 0);
            }
    }

    // epilogue: C/D layout col=lane&15, row=(lane>>4)*4+reg
    const int rq = lane >> 4;
#pragma unroll
    for (int mt = 0; mt < 4; ++mt)
#pragma unroll
        for (int nt = 0; nt < 4; ++nt) {
            int col = n0 + wn * 64 + nt * 16 + lm;
#pragma unroll
            for (int r = 0; r < 4; ++r) {
                int row = m0 + wm * 64 + mt * 16 + rq * 4 + r;
                C[(size_t)row * ldc + col] = acc[mt][nt][r];
            }
        }
}

// ---------- K3: sigmoid(r), RoPE(r,k), kv = k*v  (in place in rkv) ----------
__global__ __launch_bounds__(256)
void k_rope(float* __restrict__ rkv, const float* __restrict__ cosp, const float* __restrict__ sinp) {
    int g = blockIdx.x * 256 + threadIdx.x;   // over B*S*H*32
    int d = g & 31;
    int h = (g >> 5) & 15;
    int m = g >> 9;
    int s = m & (S_LEN - 1);
    size_t base = (size_t)m * N_RKV + h * HD + d;
    float r0 = rkv[base],        r1 = rkv[base + 32];
    float k0 = rkv[base + 1024], k1 = rkv[base + 1056];
    float v0 = rkv[base + 2048], v1 = rkv[base + 2080];
    float c0  = cosp[s * HD + d], c1  = cosp[s * HD + d + 32];
    float sn0 = sinp[s * HD + d], sn1 = sinp[s * HD + d + 32];
    r0 = 1.f / (1.f + expf(-r0));
    r1 = 1.f / (1.f + expf(-r1));
    float rr0 = r0 * c0 - r1 * sn0;
    float rr1 = r1 * c1 + r0 * sn1;
    float kk0 = k0 * c0 - k1 * sn0;
    float kk1 = k1 * c1 + k0 * sn1;
    rkv[base]        = rr0;
    rkv[base + 32]   = rr1;
    rkv[base + 1024] = kk0 * v0;  // kv
    rkv[base + 1056] = kk1 * v1;
}

// ---------- K4: per-chunk weighted sums ----------
__global__ __launch_bounds__(64)
void k_chunk_sums(const float* __restrict__ rkv, const float* __restrict__ a_ptr,
                  float* __restrict__ Cb) {
    int bid = blockIdx.x;            // bh*NC + c
    int c  = bid & (NC - 1);
    int bh = bid >> 5;
    int b = bh >> 4, h = bh & 15;
    int d = threadIdx.x;
    float a = a_ptr[0];
    float acc = 0.f;
    const float* p = rkv + (size_t)(b * S_LEN + c * CS) * N_RKV + 1024 + h * HD + d;
    for (int j = 0; j < CS; ++j) {
        acc += expf(a * (float)j) * (*p);
        p += N_RKV;
    }
    Cb[(size_t)bid * 64 + d] = acc;
}

// ---------- K5: exclusive chunk suffix ----------
__global__ __launch_bounds__(64)
void k_chunk_suffix(const float* __restrict__ Cb, const float* __restrict__ a_ptr,
                    float* __restrict__ Sb) {
    int bh = blockIdx.x;
    int d = threadIdx.x;
    float a = a_ptr[0];
    float eaCS = expf(a * (float)CS);
    float run = 0.f;
    Sb[(size_t)(bh * NC + NC - 1) * 64 + d] = 0.f;
    for (int c = NC - 2; c >= 0; --c) {
        run = Cb[(size_t)(bh * NC + c + 1) * 64 + d] + eaCS * run;
        Sb[(size_t)(bh * NC + c) * 64 + d] = run;
    }
}

// ---------- K6: in-chunk suffix scan + epilogue, write out as bf16 hi/lo into v-slot ----------
__global__ __launch_bounds__(64)
void k_wkv(float* __restrict__ rkv, const float* __restrict__ Sb,
           const float* __restrict__ a_ptr, const float* __restrict__ tf) {
    int bid = blockIdx.x;            // bh*NC + c
    int c  = bid & (NC - 1);
    int bh = bid >> 5;
    int b = bh >> 4, h = bh & 15;
    int d = threadIdx.x;
    float a = a_ptr[0];
    float ea = expf(a);
    float em1a = expm1f(a);
    float S_run = Sb[(size_t)bid * 64 + d];
    float tfv = tf[h * HD + d];
    int j = h * HD + d;              // column within row
    for (int i = CS - 1; i >= 0; --i) {
        int ig = c * CS + i;
        size_t rowb = (size_t)(b * S_LEN + ig) * N_RKV;
        float kv = rkv[rowb + 1024 + j];
        S_run = kv + ea * S_run;
        float Z = expm1f(a * (float)(S_LEN - ig)) / em1a + 1e-8f;
        float wkv = S_run / Z;
        float rr = rkv[rowb + j];
        float o = rr * (tfv * kv + wkv);
        BSplit s = bsplit(o);
        unsigned short* orow = (unsigned short*)(rkv + rowb + 2048);  // dead v-slot
        orow[j]        = s.hi;
        orow[1024 + j] = s.lo;
    }
}

extern "C" void kernel_launch(void* const* d_in, const int* in_sizes, int n_in,
                              void* d_out, int out_size, void* d_ws, size_t ws_size,
                              hipStream_t stream) {
    const float* hs    = (const float*)d_in[0];
    const float* cosp  = (const float*)d_in[1];
    const float* sinp  = (const float*)d_in[2];
    const float* W_rkv = (const float*)d_in[3];
    const float* W_o   = (const float*)d_in[4];
    const float* td    = (const float*)d_in[5];
    const float* tf    = (const float*)d_in[6];
    const float* tm    = (const float*)d_in[7];
    float* out = (float*)d_out;

    char* w = (char*)d_ws;
    float*          rkv = (float*)w;                                   // 96 MiB
    unsigned short* Ah  = (unsigned short*)(w + 100663296);            // 16 MiB
    unsigned short* Al  = (unsigned short*)(w + 100663296 + 16777216); // 16 MiB
    unsigned short* Wrh = (unsigned short*)(w + 134217728);            // 6 MiB
    unsigned short* Wrl = (unsigned short*)(w + 134217728 + 6291456);  // 6 MiB
    unsigned short* Woh = (unsigned short*)(w + 146800640);            // 2 MiB
    unsigned short* Wol = (unsigned short*)(w + 146800640 + 2097152);  // 2 MiB
    float*          Cb  = (float*)(w + 150994944);
    float*          Sb  = Cb + (size_t)BATCH * NH * NC * 64;
    float*        a_ptr = Sb + (size_t)BATCH * NH * NC * 64;

    k_avg_decay<<<1, 64, 0, stream>>>(td, a_ptr);

    k_split_mix<<<(M_TOTAL * HIDN / 4) / 256, 256, 0, stream>>>(hs, tm, Ah, Al);
    k_split_w<<<(N_RKV * HIDN / 4) / 256, 256, 0, stream>>>(W_rkv, Wrh, Wrl);
    k_split_w<<<(HIDN * HIDN / 4) / 256, 256, 0, stream>>>(W_o, Woh, Wol);

    dim3 g1(N_RKV / 128, M_TOTAL / 128);
    k_mfma_gemm<<<g1, 256, 0, stream>>>(Ah, Al, HIDN, Wrh, Wrl, HIDN, rkv, N_RKV);

    k_rope<<<(M_TOTAL * NH * 32) / 256, 256, 0, stream>>>(rkv, cosp, sinp);

    k_chunk_sums<<<BATCH * NH * NC, 64, 0, stream>>>(rkv, a_ptr, Cb);
    k_chunk_suffix<<<BATCH * NH, 64, 0, stream>>>(Cb, a_ptr, Sb);
    k_wkv<<<BATCH * NH * NC, 64, 0, stream>>>(rkv, Sb, a_ptr, tf);

    // GEMM2: A = out hi/lo packed in rkv's v-slot (elem stride 6144, hi at +4096, lo at +5120)
    dim3 g2(HIDN / 128, M_TOTAL / 128);
    k_mfma_gemm<<<g2, 256, 0, stream>>>((unsigned short*)rkv + 4096, (unsigned short*)rkv + 5120, 6144,
                                        Woh, Wol, HIDN, out, HIDN);
}

// Round 4
// 385.223 us; speedup vs baseline: 3.4348x; 1.1168x over previous
//
#include <hip/hip_runtime.h>
#include <math.h>

#define S_LEN 4096
#define HIDN  1024
#define NH    16
#define HD    64
#define BATCH 2
#define M_TOTAL (BATCH * S_LEN)   // 8192
#define N_RKV   (3 * HIDN)        // 3072
#define CS 128
#define NC (S_LEN / CS)           // 32

typedef __attribute__((ext_vector_type(8))) short bf16x8;
typedef __attribute__((ext_vector_type(4))) float f32x4;
typedef __attribute__((ext_vector_type(4))) unsigned short u16x4;

// ---------- bf16 split helpers (manual RNE, bit-exact) ----------
__device__ __forceinline__ unsigned short f2bf_rne(float x) {
    unsigned int u = __float_as_uint(x);
    unsigned int r = (u + 0x7fffu + ((u >> 16) & 1u)) >> 16;
    return (unsigned short)r;
}
__device__ __forceinline__ float bf2f(unsigned short h) {
    return __uint_as_float(((unsigned int)h) << 16);
}
struct BSplit { unsigned short hi, lo; };
__device__ __forceinline__ BSplit bsplit(float x) {
    BSplit r;
    r.hi = f2bf_rne(x);
    r.lo = f2bf_rne(x - bf2f(r.hi));
    return r;
}

// ---------- async global->LDS, 16B per lane ----------
__device__ __forceinline__ void load_lds16(const void* g, void* l) {
    __builtin_amdgcn_global_load_lds((const __attribute__((address_space(1))) void*)g,
                                     (__attribute__((address_space(3))) void*)l, 16, 0, 0);
}

// ---------- K0: a = mean(exp(time_decay)) ----------
__global__ void k_avg_decay(const float* __restrict__ td, float* __restrict__ a_out) {
    int t = threadIdx.x;
    double acc = 0.0;
    for (int i = t; i < NH * HD; i += 64) acc += exp((double)td[i]);
    for (int off = 32; off > 0; off >>= 1) acc += __shfl_down(acc, off, 64);
    if (t == 0) a_out[0] = (float)(acc / (double)(NH * HD));
}

// ---------- K1a: mixed = hs*tm + shift(hs)*(1-tm), split to bf16 hi/lo ----------
__global__ __launch_bounds__(256)
void k_split_mix(const float* __restrict__ hs, const float* __restrict__ tm,
                 unsigned short* __restrict__ Ah, unsigned short* __restrict__ Al) {
    int g = blockIdx.x * 256 + threadIdx.x;      // over M_TOTAL * (HIDN/4)
    int kc = (g & 255) * 4;
    int m = g >> 8;
    float4 cur = *(const float4*)&hs[(size_t)m * HIDN + kc];
    float4 t4  = *(const float4*)&tm[kc];
    float4 prev = make_float4(0.f, 0.f, 0.f, 0.f);
    if (m & (S_LEN - 1)) prev = *(const float4*)&hs[(size_t)(m - 1) * HIDN + kc];
    float x0 = cur.x * t4.x + prev.x * (1.f - t4.x);
    float x1 = cur.y * t4.y + prev.y * (1.f - t4.y);
    float x2 = cur.z * t4.z + prev.z * (1.f - t4.z);
    float x3 = cur.w * t4.w + prev.w * (1.f - t4.w);
    BSplit s0 = bsplit(x0), s1 = bsplit(x1), s2 = bsplit(x2), s3 = bsplit(x3);
    u16x4 h, l;
    h.x = s0.hi; h.y = s1.hi; h.z = s2.hi; h.w = s3.hi;
    l.x = s0.lo; l.y = s1.lo; l.z = s2.lo; l.w = s3.lo;
    size_t o = (size_t)m * HIDN + kc;
    *(u16x4*)&Ah[o] = h;
    *(u16x4*)&Al[o] = l;
}

// ---------- K1b: flat fp32 -> bf16 hi/lo split (weights) ----------
__global__ __launch_bounds__(256)
void k_split_w(const float* __restrict__ W,
               unsigned short* __restrict__ Wh, unsigned short* __restrict__ Wl) {
    int g = blockIdx.x * 256 + threadIdx.x;
    size_t o = (size_t)g * 4;
    float4 v = *(const float4*)&W[o];
    BSplit s0 = bsplit(v.x), s1 = bsplit(v.y), s2 = bsplit(v.z), s3 = bsplit(v.w);
    u16x4 h, l;
    h.x = s0.hi; h.y = s1.hi; h.z = s2.hi; h.w = s3.hi;
    l.x = s0.lo; l.y = s1.lo; l.z = s2.lo; l.w = s3.lo;
    *(u16x4*)&Wh[o] = h;
    *(u16x4*)&Wl[o] = l;
}

// ---------- K2: split-bf16 MFMA GEMM  C[m][n] = sum_k A[m][k] * B[n][k] ----------
__global__ __launch_bounds__(256, 2)
void k_mfma_gemm(const unsigned short* __restrict__ Ah, const unsigned short* __restrict__ Al, int lda,
                 const unsigned short* __restrict__ Bh, const unsigned short* __restrict__ Bl, int ldb,
                 float* __restrict__ C, int ldc)
{
    __shared__ unsigned short smem[16384];       // 32 KB
    const int tid  = threadIdx.x;
    const int lane = tid & 63;
    const int wave = tid >> 6;
    const int wm = wave >> 1, wn = wave & 1;
    const int m0 = blockIdx.y * 128;
    const int n0 = blockIdx.x * 128;

    const unsigned short* gsrc;
    int ld;
    {
        int row0 = (wave < 2) ? m0 : n0;
        const unsigned short* base = (wave == 0) ? Ah : (wave == 1) ? Al : (wave == 2) ? Bh : Bl;
        ld = (wave < 2) ? lda : ldb;
        int rowoff = lane >> 2;
        int q = (lane & 3) ^ ((lane >> 2) & 3);
        gsrc = base + (size_t)(row0 + rowoff) * ld + q * 8;
    }
    unsigned short* ldsbase = smem + wave * 4096;

    const int lm = lane & 15;
    const int qx = (lane >> 4) ^ (lane & 3);
    int aoff[4], boff[4];
#pragma unroll
    for (int t = 0; t < 4; ++t) {
        aoff[t] = (wm * 64 + t * 16 + lm) * 32 + qx * 8;
        boff[t] = 8192 + (wn * 64 + t * 16 + lm) * 32 + qx * 8;
    }

    f32x4 acc[4][4] = {};

    for (int kt = 0; kt < 1024; kt += 32) {
        __syncthreads();
        const unsigned short* g = gsrc + kt;
#pragma unroll
        for (int i = 0; i < 8; ++i)
            load_lds16(g + (size_t)i * 16 * ld, ldsbase + i * 512);
        __syncthreads();

        bf16x8 fah[4], fal[4], fbh[4], fbl[4];
#pragma unroll
        for (int t = 0; t < 4; ++t) {
            fah[t] = *(const bf16x8*)(smem + aoff[t]);
            fal[t] = *(const bf16x8*)(smem + 4096 + aoff[t]);
            fbh[t] = *(const bf16x8*)(smem + boff[t]);
            fbl[t] = *(const bf16x8*)(smem + 4096 + boff[t]);
        }
#pragma unroll
        for (int mt = 0; mt < 4; ++mt)
#pragma unroll
            for (int nt = 0; nt < 4; ++nt) {
                acc[mt][nt] = __builtin_amdgcn_mfma_f32_16x16x32_bf16(fah[mt], fbh[nt], acc[mt][nt], 0, 0, 0);
                acc[mt][nt] = __builtin_amdgcn_mfma_f32_16x16x32_bf16(fah[mt], fbl[nt], acc[mt][nt], 0, 0, 0);
                acc[mt][nt] = __builtin_amdgcn_mfma_f32_16x16x32_bf16(fal[mt], fbh[nt], acc[mt][nt], 0, 0, 0);
            }
    }

    const int rq = lane >> 4;
#pragma unroll
    for (int mt = 0; mt < 4; ++mt)
#pragma unroll
        for (int nt = 0; nt < 4; ++nt) {
            int col = n0 + wn * 64 + nt * 16 + lm;
#pragma unroll
            for (int r = 0; r < 4; ++r) {
                int row = m0 + wm * 64 + mt * 16 + rq * 4 + r;
                C[(size_t)row * ldc + col] = acc[mt][nt][r];
            }
        }
}

// ---------- K3+K4 fused: sigmoid/RoPE/kv in-place + per-chunk weighted sums ----------
// One block per (bh, c): 256 threads, wave w handles rows j = w, w+4, ..., w+124.
// Lane = d in [0,64); RoPE partner (d^32) via shfl_xor.
__global__ __launch_bounds__(256)
void k_rope_sums(float* __restrict__ rkv, const float* __restrict__ cosp,
                 const float* __restrict__ sinp, const float* __restrict__ a_ptr,
                 float* __restrict__ Cb) {
    __shared__ float red[4][64];
    int bid = blockIdx.x;                // bh*NC + c
    int c  = bid & (NC - 1);
    int bh = bid >> 5;
    int b = bh >> 4, h = bh & 15;
    int lane = threadIdx.x & 63;
    int wave = threadIdx.x >> 6;
    float a = a_ptr[0];
    float w  = expf(a * (float)wave);    // absolute weight e^{a*j}, j starts at wave
    float w4 = expf(a * 4.f);
    float sgn = (lane < 32) ? -1.f : 1.f;
    float acc = 0.f;
    int sbase = c * CS;
    size_t rowS0 = (size_t)(b * S_LEN + sbase + wave) * N_RKV;
    int j = h * HD + lane;
#pragma unroll 4
    for (int t = 0; t < 32; ++t) {
        size_t rowS = rowS0 + (size_t)t * 4 * N_RKV;
        int s = sbase + wave + 4 * t;
        float r = rkv[rowS + j];
        float k = rkv[rowS + 1024 + j];
        float v = rkv[rowS + 2048 + j];
        float cs = cosp[s * HD + lane];
        float sn = sinp[s * HD + lane];
        float sig = 1.f / (1.f + expf(-r));
        float sigp = __shfl_xor(sig, 32, 64);
        float kp   = __shfl_xor(k, 32, 64);
        float rr = sig * cs + sgn * sigp * sn;
        float kk = k * cs + sgn * kp * sn;
        float kv = kk * v;
        rkv[rowS + j]        = rr;
        rkv[rowS + 1024 + j] = kv;
        acc += w * kv;
        w *= w4;
    }
    red[wave][lane] = acc;
    __syncthreads();
    if (wave == 0) {
        float tot = red[0][lane] + red[1][lane] + red[2][lane] + red[3][lane];
        Cb[(size_t)bid * 64 + lane] = tot;
    }
}

// ---------- K5: exclusive chunk suffix ----------
__global__ __launch_bounds__(64)
void k_chunk_suffix(const float* __restrict__ Cb, const float* __restrict__ a_ptr,
                    float* __restrict__ Sb) {
    int bh = blockIdx.x;
    int d = threadIdx.x;
    float a = a_ptr[0];
    float eaCS = expf(a * (float)CS);
    float run = 0.f;
    Sb[(size_t)(bh * NC + NC - 1) * 64 + d] = 0.f;
    for (int c = NC - 2; c >= 0; --c) {
        run = Cb[(size_t)(bh * NC + c + 1) * 64 + d] + eaCS * run;
        Sb[(size_t)(bh * NC + c) * 64 + d] = run;
    }
}

// ---------- K6: parallel in-chunk suffix scan + epilogue (bf16 hi/lo into v-slot) ----------
// One block per (bh, c): wave w owns rows [32w, 32w+32). Phase 1: load kv,r into
// registers + local weighted sum T_w. Phase 2: combine T_{w'}, Sb. Phase 3: 32-step
// register-only recurrence + store.
__global__ __launch_bounds__(256)
void k_wkv2(float* __restrict__ rkv, const float* __restrict__ Sb,
            const float* __restrict__ a_ptr, const float* __restrict__ tf) {
    __shared__ float Tl[4][64];
    int bid = blockIdx.x;                // bh*NC + c
    int c  = bid & (NC - 1);
    int bh = bid >> 5;
    int b = bh >> 4, h = bh & 15;
    int lane = threadIdx.x & 63;
    int wave = threadIdx.x >> 6;
    float a = a_ptr[0];
    float ea = expf(a);
    float em1a = expm1f(a);
    int j = h * HD + lane;
    size_t rowS0 = (size_t)(b * S_LEN + c * CS + wave * 32) * N_RKV;

    float kvreg[32], rreg[32];
    float w = 1.f, T = 0.f;
#pragma unroll
    for (int t = 0; t < 32; ++t) {
        size_t rowS = rowS0 + (size_t)t * N_RKV;
        kvreg[t] = rkv[rowS + 1024 + j];
        rreg[t]  = rkv[rowS + j];
        T += w * kvreg[t];
        w *= ea;
    }
    Tl[wave][lane] = T;
    __syncthreads();

    float e32 = expf(a * 32.f);
    float S_run = Sb[(size_t)bid * 64 + lane] * expf(a * 32.f * (float)(3 - wave));
    float f = 1.f;
    for (int wp = wave + 1; wp < 4; ++wp) {
        S_run += f * Tl[wp][lane];
        f *= e32;
    }
    float tfv = tf[j];
#pragma unroll
    for (int t = 31; t >= 0; --t) {
        float kv = kvreg[t];
        S_run = kv + ea * S_run;
        int ig = c * CS + wave * 32 + t;
        float Z = expm1f(a * (float)(S_LEN - ig)) / em1a + 1e-8f;
        float o = rreg[t] * (tfv * kv + S_run / Z);
        BSplit s = bsplit(o);
        size_t rowS = rowS0 + (size_t)t * N_RKV;
        unsigned short* orow = (unsigned short*)(rkv + rowS + 2048);
        orow[j]        = s.hi;
        orow[1024 + j] = s.lo;
    }
}

extern "C" void kernel_launch(void* const* d_in, const int* in_sizes, int n_in,
                              void* d_out, int out_size, void* d_ws, size_t ws_size,
                              hipStream_t stream) {
    const float* hs    = (const float*)d_in[0];
    const float* cosp  = (const float*)d_in[1];
    const float* sinp  = (const float*)d_in[2];
    const float* W_rkv = (const float*)d_in[3];
    const float* W_o   = (const float*)d_in[4];
    const float* td    = (const float*)d_in[5];
    const float* tf    = (const float*)d_in[6];
    const float* tm    = (const float*)d_in[7];
    float* out = (float*)d_out;

    char* w = (char*)d_ws;
    float*          rkv = (float*)w;                                   // 96 MiB
    unsigned short* Ah  = (unsigned short*)(w + 100663296);            // 16 MiB
    unsigned short* Al  = (unsigned short*)(w + 100663296 + 16777216); // 16 MiB
    unsigned short* Wrh = (unsigned short*)(w + 134217728);            // 6 MiB
    unsigned short* Wrl = (unsigned short*)(w + 134217728 + 6291456);  // 6 MiB
    unsigned short* Woh = (unsigned short*)(w + 146800640);            // 2 MiB
    unsigned short* Wol = (unsigned short*)(w + 146800640 + 2097152);  // 2 MiB
    float*          Cb  = (float*)(w + 150994944);
    float*          Sb  = Cb + (size_t)BATCH * NH * NC * 64;
    float*        a_ptr = Sb + (size_t)BATCH * NH * NC * 64;

    k_avg_decay<<<1, 64, 0, stream>>>(td, a_ptr);

    k_split_mix<<<(M_TOTAL * HIDN / 4) / 256, 256, 0, stream>>>(hs, tm, Ah, Al);
    k_split_w<<<(N_RKV * HIDN / 4) / 256, 256, 0, stream>>>(W_rkv, Wrh, Wrl);
    k_split_w<<<(HIDN * HIDN / 4) / 256, 256, 0, stream>>>(W_o, Woh, Wol);

    dim3 g1(N_RKV / 128, M_TOTAL / 128);
    k_mfma_gemm<<<g1, 256, 0, stream>>>(Ah, Al, HIDN, Wrh, Wrl, HIDN, rkv, N_RKV);

    k_rope_sums<<<BATCH * NH * NC, 256, 0, stream>>>(rkv, cosp, sinp, a_ptr, Cb);
    k_chunk_suffix<<<BATCH * NH, 64, 0, stream>>>(Cb, a_ptr, Sb);
    k_wkv2<<<BATCH * NH * NC, 256, 0, stream>>>(rkv, Sb, a_ptr, tf);

    // GEMM2: A = out hi/lo packed in rkv's v-slot (elem stride 6144, hi at +4096, lo at +5120)
    dim3 g2(HIDN / 128, M_TOTAL / 128);
    k_mfma_gemm<<<g2, 256, 0, stream>>>((unsigned short*)rkv + 4096, (unsigned short*)rkv + 5120, 6144,
                                        Woh, Wol, HIDN, out, HIDN);
}

// Round 5
// 335.626 us; speedup vs baseline: 3.9424x; 1.1478x over previous
//
#include <hip/hip_runtime.h>
#include <math.h>

#define S_LEN 4096
#define HIDN  1024
#define NH    16
#define HD    64
#define BATCH 2
#define M_TOTAL (BATCH * S_LEN)   // 8192
#define N_RKV   (3 * HIDN)        // 3072
#define CS 128
#define NC (S_LEN / CS)           // 32

typedef __attribute__((ext_vector_type(8))) _Float16 f16x8;
typedef __attribute__((ext_vector_type(4))) float f32x4;
typedef __attribute__((ext_vector_type(4))) unsigned short u16x4;

// ---------- fp16 split helpers (RNE via hardware cvt) ----------
__device__ __forceinline__ unsigned short f2h(float x) {
    _Float16 h = (_Float16)x;
    return *(unsigned short*)&h;
}
__device__ __forceinline__ float h2f(unsigned short b) {
    _Float16 h = *(_Float16*)&b;
    return (float)h;
}
struct HSplit { unsigned short hi, lo; };
__device__ __forceinline__ HSplit hsplit(float x) {
    HSplit r;
    r.hi = f2h(x);
    r.lo = f2h(x - h2f(r.hi));
    return r;
}

// ---------- async global->LDS, 16B per lane ----------
__device__ __forceinline__ void load_lds16(const void* g, void* l) {
    __builtin_amdgcn_global_load_lds((const __attribute__((address_space(1))) void*)g,
                                     (__attribute__((address_space(3))) void*)l, 16, 0, 0);
}

// ---------- K0: a = mean(exp(time_decay)) ----------
__global__ void k_avg_decay(const float* __restrict__ td, float* __restrict__ a_out) {
    int t = threadIdx.x;
    double acc = 0.0;
    for (int i = t; i < NH * HD; i += 64) acc += exp((double)td[i]);
    for (int off = 32; off > 0; off >>= 1) acc += __shfl_down(acc, off, 64);
    if (t == 0) a_out[0] = (float)(acc / (double)(NH * HD));
}

// ---------- K1a: mixed = hs*tm + shift(hs)*(1-tm), split to fp16 hi/lo ----------
__global__ __launch_bounds__(256)
void k_split_mix(const float* __restrict__ hs, const float* __restrict__ tm,
                 unsigned short* __restrict__ Ah, unsigned short* __restrict__ Al) {
    int g = blockIdx.x * 256 + threadIdx.x;      // over M_TOTAL * (HIDN/4)
    int kc = (g & 255) * 4;
    int m = g >> 8;
    float4 cur = *(const float4*)&hs[(size_t)m * HIDN + kc];
    float4 t4  = *(const float4*)&tm[kc];
    float4 prev = make_float4(0.f, 0.f, 0.f, 0.f);
    if (m & (S_LEN - 1)) prev = *(const float4*)&hs[(size_t)(m - 1) * HIDN + kc];
    float x0 = cur.x * t4.x + prev.x * (1.f - t4.x);
    float x1 = cur.y * t4.y + prev.y * (1.f - t4.y);
    float x2 = cur.z * t4.z + prev.z * (1.f - t4.z);
    float x3 = cur.w * t4.w + prev.w * (1.f - t4.w);
    HSplit s0 = hsplit(x0), s1 = hsplit(x1), s2 = hsplit(x2), s3 = hsplit(x3);
    u16x4 h, l;
    h.x = s0.hi; h.y = s1.hi; h.z = s2.hi; h.w = s3.hi;
    l.x = s0.lo; l.y = s1.lo; l.z = s2.lo; l.w = s3.lo;
    size_t o = (size_t)m * HIDN + kc;
    *(u16x4*)&Ah[o] = h;
    *(u16x4*)&Al[o] = l;
}

// ---------- K1b: flat fp32 -> plain fp16 (weights) ----------
__global__ __launch_bounds__(256)
void k_split_w(const float* __restrict__ W, unsigned short* __restrict__ Wh) {
    int g = blockIdx.x * 256 + threadIdx.x;
    size_t o = (size_t)g * 4;
    float4 v = *(const float4*)&W[o];
    u16x4 h;
    h.x = f2h(v.x); h.y = f2h(v.y); h.z = f2h(v.z); h.w = f2h(v.w);
    *(u16x4*)&Wh[o] = h;
}

// ---------- K2: 2-term split-fp16 MFMA GEMM  C[m][n] = sum_k A[m][k] * B[n][k] ----------
// A = Ah+Al (fp16 hi/lo), B plain fp16. 2 MFMA terms: Ah*B + Al*B.
// 128x128 tile, BK=32, 256 threads (4 waves, 2x2 of 64x64).
// LDS: 3 tiles (Ah, Al, B) x 8KB = 24KB, XOR-swizzled 16B chunks.
__global__ __launch_bounds__(256, 2)
void k_mfma_gemm(const unsigned short* __restrict__ Ah, const unsigned short* __restrict__ Al, int lda,
                 const unsigned short* __restrict__ Bm, int ldb,
                 float* __restrict__ C, int ldc)
{
    __shared__ unsigned short smem[12288];       // 24 KB
    const int tid  = threadIdx.x;
    const int lane = tid & 63;
    const int wave = tid >> 6;
    const int wm = wave >> 1, wn = wave & 1;
    const int m0 = blockIdx.y * 128;
    const int n0 = blockIdx.x * 128;

    // staging: waves 0,1 stage Ah,Al (8 segs each); waves 2,3 stage B halves (4 segs each)
    const unsigned short* gsrc;
    size_t gstep;
    int segbase, nseg;
    {
        int rowoff = lane >> 2;
        int q = (lane & 3) ^ ((lane >> 2) & 3);
        if (wave < 2) {
            const unsigned short* base = (wave == 0) ? Ah : Al;
            gsrc = base + (size_t)(m0 + rowoff) * lda + q * 8;
            gstep = (size_t)16 * lda;
            segbase = wave * 8; nseg = 8;
        } else {
            gsrc = Bm + (size_t)(n0 + (wave - 2) * 64 + rowoff) * ldb + q * 8;
            gstep = (size_t)16 * ldb;
            segbase = 16 + (wave - 2) * 4; nseg = 4;
        }
    }

    const int lm = lane & 15;
    const int qx = (lane >> 4) ^ (lane & 3);
    int aoff[4], boff[4];
#pragma unroll
    for (int t = 0; t < 4; ++t) {
        aoff[t] = (wm * 64 + t * 16 + lm) * 32 + qx * 8;
        boff[t] = 8192 + (wn * 64 + t * 16 + lm) * 32 + qx * 8;
    }

    f32x4 acc[4][4] = {};

    for (int kt = 0; kt < 1024; kt += 32) {
        __syncthreads();
        const unsigned short* g = gsrc + kt;
        if (wave < 2) {
#pragma unroll
            for (int i = 0; i < 8; ++i)
                load_lds16(g + (size_t)i * gstep, smem + (segbase + i) * 512);
        } else {
#pragma unroll
            for (int i = 0; i < 4; ++i)
                load_lds16(g + (size_t)i * gstep, smem + (segbase + i) * 512);
        }
        __syncthreads();

        f16x8 fah[4], fal[4], fb[4];
#pragma unroll
        for (int t = 0; t < 4; ++t) {
            fah[t] = *(const f16x8*)(smem + aoff[t]);
            fal[t] = *(const f16x8*)(smem + 4096 + aoff[t]);
            fb[t]  = *(const f16x8*)(smem + boff[t]);
        }
#pragma unroll
        for (int mt = 0; mt < 4; ++mt)
#pragma unroll
            for (int nt = 0; nt < 4; ++nt) {
                acc[mt][nt] = __builtin_amdgcn_mfma_f32_16x16x32_f16(fah[mt], fb[nt], acc[mt][nt], 0, 0, 0);
                acc[mt][nt] = __builtin_amdgcn_mfma_f32_16x16x32_f16(fal[mt], fb[nt], acc[mt][nt], 0, 0, 0);
            }
    }

    // epilogue: C/D layout col=lane&15, row=(lane>>4)*4+reg
    const int rq = lane >> 4;
#pragma unroll
    for (int mt = 0; mt < 4; ++mt)
#pragma unroll
        for (int nt = 0; nt < 4; ++nt) {
            int col = n0 + wn * 64 + nt * 16 + lm;
#pragma unroll
            for (int r = 0; r < 4; ++r) {
                int row = m0 + wm * 64 + mt * 16 + rq * 4 + r;
                C[(size_t)row * ldc + col] = acc[mt][nt][r];
            }
        }
}

// ---------- K3+K4 fused: sigmoid/RoPE/kv in-place + per-chunk weighted sums ----------
__global__ __launch_bounds__(256)
void k_rope_sums(float* __restrict__ rkv, const float* __restrict__ cosp,
                 const float* __restrict__ sinp, const float* __restrict__ a_ptr,
                 float* __restrict__ Cb) {
    __shared__ float red[4][64];
    int bid = blockIdx.x;                // bh*NC + c
    int c  = bid & (NC - 1);
    int bh = bid >> 5;
    int b = bh >> 4, h = bh & 15;
    int lane = threadIdx.x & 63;
    int wave = threadIdx.x >> 6;
    float a = a_ptr[0];
    float w  = expf(a * (float)wave);
    float w4 = expf(a * 4.f);
    float sgn = (lane < 32) ? -1.f : 1.f;
    float acc = 0.f;
    int sbase = c * CS;
    size_t rowS0 = (size_t)(b * S_LEN + sbase + wave) * N_RKV;
    int j = h * HD + lane;
#pragma unroll 4
    for (int t = 0; t < 32; ++t) {
        size_t rowS = rowS0 + (size_t)t * 4 * N_RKV;
        int s = sbase + wave + 4 * t;
        float r = rkv[rowS + j];
        float k = rkv[rowS + 1024 + j];
        float v = rkv[rowS + 2048 + j];
        float cs = cosp[s * HD + lane];
        float sn = sinp[s * HD + lane];
        float sig = 1.f / (1.f + expf(-r));
        float sigp = __shfl_xor(sig, 32, 64);
        float kp   = __shfl_xor(k, 32, 64);
        float rr = sig * cs + sgn * sigp * sn;
        float kk = k * cs + sgn * kp * sn;
        float kv = kk * v;
        rkv[rowS + j]        = rr;
        rkv[rowS + 1024 + j] = kv;
        acc += w * kv;
        w *= w4;
    }
    red[wave][lane] = acc;
    __syncthreads();
    if (wave == 0) {
        float tot = red[0][lane] + red[1][lane] + red[2][lane] + red[3][lane];
        Cb[(size_t)bid * 64 + lane] = tot;
    }
}

// ---------- K5: exclusive chunk suffix ----------
__global__ __launch_bounds__(64)
void k_chunk_suffix(const float* __restrict__ Cb, const float* __restrict__ a_ptr,
                    float* __restrict__ Sb) {
    int bh = blockIdx.x;
    int d = threadIdx.x;
    float a = a_ptr[0];
    float eaCS = expf(a * (float)CS);
    float run = 0.f;
    Sb[(size_t)(bh * NC + NC - 1) * 64 + d] = 0.f;
    for (int c = NC - 2; c >= 0; --c) {
        run = Cb[(size_t)(bh * NC + c + 1) * 64 + d] + eaCS * run;
        Sb[(size_t)(bh * NC + c) * 64 + d] = run;
    }
}

// ---------- K6: parallel in-chunk suffix scan + epilogue (fp16 hi/lo into v-slot) ----------
__global__ __launch_bounds__(256)
void k_wkv2(float* __restrict__ rkv, const float* __restrict__ Sb,
            const float* __restrict__ a_ptr, const float* __restrict__ tf) {
    __shared__ float Tl[4][64];
    int bid = blockIdx.x;                // bh*NC + c
    int c  = bid & (NC - 1);
    int bh = bid >> 5;
    int b = bh >> 4, h = bh & 15;
    int lane = threadIdx.x & 63;
    int wave = threadIdx.x >> 6;
    float a = a_ptr[0];
    float ea = expf(a);
    float em1a = expm1f(a);
    int j = h * HD + lane;
    size_t rowS0 = (size_t)(b * S_LEN + c * CS + wave * 32) * N_RKV;

    float kvreg[32], rreg[32];
    float w = 1.f, T = 0.f;
#pragma unroll
    for (int t = 0; t < 32; ++t) {
        size_t rowS = rowS0 + (size_t)t * N_RKV;
        kvreg[t] = rkv[rowS + 1024 + j];
        rreg[t]  = rkv[rowS + j];
        T += w * kvreg[t];
        w *= ea;
    }
    Tl[wave][lane] = T;
    __syncthreads();

    float e32 = expf(a * 32.f);
    float S_run = Sb[(size_t)bid * 64 + lane] * expf(a * 32.f * (float)(3 - wave));
    float f = 1.f;
    for (int wp = wave + 1; wp < 4; ++wp) {
        S_run += f * Tl[wp][lane];
        f *= e32;
    }
    float tfv = tf[j];
#pragma unroll
    for (int t = 31; t >= 0; --t) {
        float kv = kvreg[t];
        S_run = kv + ea * S_run;
        int ig = c * CS + wave * 32 + t;
        float Z = expm1f(a * (float)(S_LEN - ig)) / em1a + 1e-8f;
        float o = rreg[t] * (tfv * kv + S_run / Z);
        HSplit s = hsplit(o);
        size_t rowS = rowS0 + (size_t)t * N_RKV;
        unsigned short* orow = (unsigned short*)(rkv + rowS + 2048);
        orow[j]        = s.hi;
        orow[1024 + j] = s.lo;
    }
}

extern "C" void kernel_launch(void* const* d_in, const int* in_sizes, int n_in,
                              void* d_out, int out_size, void* d_ws, size_t ws_size,
                              hipStream_t stream) {
    const float* hs    = (const float*)d_in[0];
    const float* cosp  = (const float*)d_in[1];
    const float* sinp  = (const float*)d_in[2];
    const float* W_rkv = (const float*)d_in[3];
    const float* W_o   = (const float*)d_in[4];
    const float* td    = (const float*)d_in[5];
    const float* tf    = (const float*)d_in[6];
    const float* tm    = (const float*)d_in[7];
    float* out = (float*)d_out;

    char* w = (char*)d_ws;
    float*          rkv = (float*)w;                                   // 96 MiB
    unsigned short* Ah  = (unsigned short*)(w + 100663296);            // 16 MiB
    unsigned short* Al  = (unsigned short*)(w + 100663296 + 16777216); // 16 MiB
    unsigned short* Wrh = (unsigned short*)(w + 134217728);            // 6 MiB
    unsigned short* Woh = (unsigned short*)(w + 146800640);            // 2 MiB
    float*          Cb  = (float*)(w + 150994944);
    float*          Sb  = Cb + (size_t)BATCH * NH * NC * 64;
    float*        a_ptr = Sb + (size_t)BATCH * NH * NC * 64;

    k_avg_decay<<<1, 64, 0, stream>>>(td, a_ptr);

    k_split_mix<<<(M_TOTAL * HIDN / 4) / 256, 256, 0, stream>>>(hs, tm, Ah, Al);
    k_split_w<<<(N_RKV * HIDN / 4) / 256, 256, 0, stream>>>(W_rkv, Wrh);
    k_split_w<<<(HIDN * HIDN / 4) / 256, 256, 0, stream>>>(W_o, Woh);

    dim3 g1(N_RKV / 128, M_TOTAL / 128);
    k_mfma_gemm<<<g1, 256, 0, stream>>>(Ah, Al, HIDN, Wrh, HIDN, rkv, N_RKV);

    k_rope_sums<<<BATCH * NH * NC, 256, 0, stream>>>(rkv, cosp, sinp, a_ptr, Cb);
    k_chunk_suffix<<<BATCH * NH, 64, 0, stream>>>(Cb, a_ptr, Sb);
    k_wkv2<<<BATCH * NH * NC, 256, 0, stream>>>(rkv, Sb, a_ptr, tf);

    // GEMM2: A = out fp16 hi/lo packed in rkv's v-slot (u16 stride 6144, hi at +4096, lo at +5120)
    dim3 g2(HIDN / 128, M_TOTAL / 128);
    k_mfma_gemm<<<g2, 256, 0, stream>>>((unsigned short*)rkv + 4096, (unsigned short*)rkv + 5120, 6144,
                                        Woh, HIDN, out, HIDN);
}

// Round 6
// 308.933 us; speedup vs baseline: 4.2831x; 1.0864x over previous
//
#include <hip/hip_runtime.h>
#include <math.h>

#define S_LEN 4096
#define HIDN  1024
#define NH    16
#define HD    64
#define BATCH 2
#define M_TOTAL (BATCH * S_LEN)   // 8192
#define N_RKV   (3 * HIDN)        // 3072
#define CS 128
#define NC (S_LEN / CS)           // 32

typedef __attribute__((ext_vector_type(8))) _Float16 f16x8;
typedef __attribute__((ext_vector_type(4))) float f32x4;
typedef __attribute__((ext_vector_type(4))) unsigned short u16x4;

// ---------- fp16 split helpers ----------
__device__ __forceinline__ unsigned short f2h(float x) {
    _Float16 h = (_Float16)x;
    return *(unsigned short*)&h;
}
__device__ __forceinline__ float h2f(unsigned short b) {
    _Float16 h = *(_Float16*)&b;
    return (float)h;
}
struct HSplit { unsigned short hi, lo; };
__device__ __forceinline__ HSplit hsplit(float x) {
    HSplit r;
    r.hi = f2h(x);
    r.lo = f2h(x - h2f(r.hi));
    return r;
}

// ---------- async global->LDS, 16B per lane ----------
__device__ __forceinline__ void load_lds16(const void* g, void* l) {
    __builtin_amdgcn_global_load_lds((const __attribute__((address_space(1))) void*)g,
                                     (__attribute__((address_space(3))) void*)l, 16, 0, 0);
}

// ---------- K0: a = mean(exp(time_decay)) ----------
__global__ void k_avg_decay(const float* __restrict__ td, float* __restrict__ a_out) {
    int t = threadIdx.x;
    double acc = 0.0;
    for (int i = t; i < NH * HD; i += 64) acc += exp((double)td[i]);
    for (int off = 32; off > 0; off >>= 1) acc += __shfl_down(acc, off, 64);
    if (t == 0) a_out[0] = (float)(acc / (double)(NH * HD));
}

// ---------- K1a: mixed = hs*tm + shift(hs)*(1-tm), split to fp16 hi/lo ----------
__global__ __launch_bounds__(256)
void k_split_mix(const float* __restrict__ hs, const float* __restrict__ tm,
                 unsigned short* __restrict__ Ah, unsigned short* __restrict__ Al) {
    int g = blockIdx.x * 256 + threadIdx.x;      // over M_TOTAL * (HIDN/4)
    int kc = (g & 255) * 4;
    int m = g >> 8;
    float4 cur = *(const float4*)&hs[(size_t)m * HIDN + kc];
    float4 t4  = *(const float4*)&tm[kc];
    float4 prev = make_float4(0.f, 0.f, 0.f, 0.f);
    if (m & (S_LEN - 1)) prev = *(const float4*)&hs[(size_t)(m - 1) * HIDN + kc];
    float x0 = cur.x * t4.x + prev.x * (1.f - t4.x);
    float x1 = cur.y * t4.y + prev.y * (1.f - t4.y);
    float x2 = cur.z * t4.z + prev.z * (1.f - t4.z);
    float x3 = cur.w * t4.w + prev.w * (1.f - t4.w);
    HSplit s0 = hsplit(x0), s1 = hsplit(x1), s2 = hsplit(x2), s3 = hsplit(x3);
    u16x4 h, l;
    h.x = s0.hi; h.y = s1.hi; h.z = s2.hi; h.w = s3.hi;
    l.x = s0.lo; l.y = s1.lo; l.z = s2.lo; l.w = s3.lo;
    size_t o = (size_t)m * HIDN + kc;
    *(u16x4*)&Ah[o] = h;
    *(u16x4*)&Al[o] = l;
}

// ---------- K1b: flat fp32 -> plain fp16 (weights) ----------
__global__ __launch_bounds__(256)
void k_split_w(const float* __restrict__ W, unsigned short* __restrict__ Wh) {
    int g = blockIdx.x * 256 + threadIdx.x;
    size_t o = (size_t)g * 4;
    float4 v = *(const float4*)&W[o];
    u16x4 h;
    h.x = f2h(v.x); h.y = f2h(v.y); h.z = f2h(v.z); h.w = f2h(v.w);
    *(u16x4*)&Wh[o] = h;
}

__device__ __forceinline__ f32x4 mfma16(f16x8 a, f16x8 b, f32x4 c) {
    return __builtin_amdgcn_mfma_f32_16x16x32_f16(a, b, c, 0, 0, 0);
}

// ---------- K2: fused GEMM1 + sigmoid/RoPE/kv + chunk sums ----------
// Block: one head (64 cols of r,k,v) x one 128-row chunk. A = Ah+Al fp16 split,
// W fp16. 4 waves each own 32 rows. Epilogue: RoPE pairs are (nt, nt+2) in the
// SAME lane; writes head-major rP/kvP [bh][s][64] and chunk sums Cb.
__global__ __launch_bounds__(256)
void k_gemm1_fused(const unsigned short* __restrict__ Ahg, const unsigned short* __restrict__ Alg,
                   const unsigned short* __restrict__ Wr,
                   const float* __restrict__ cosp, const float* __restrict__ sinp,
                   const float* __restrict__ a_ptr,
                   float* __restrict__ rP, float* __restrict__ kvP, float* __restrict__ Cb)
{
    // LDS: Ah[0,4096) Al[4096,8192) Br[8192,10240) Bk[10240,12288) Bv[12288,14336)
    __shared__ unsigned short smem[14336];   // 28 KB
    const int tid  = threadIdx.x;
    const int lane = tid & 63;
    const int wave = tid >> 6;
    const int h  = blockIdx.x;          // 0..15
    const int mc = blockIdx.y;          // 0..63
    const int m0 = mc * 128;
    const int b  = mc >> 5;
    const int c  = mc & 31;
    const int bh = b * NH + h;

    // staging: 28 segments of 16 rows x 32 k; wave handles segs [7w, 7w+7)
    const unsigned short* segsrc[7];
    int segdst[7];
    {
        int rowoff = lane >> 2;
        int q = (lane & 3) ^ (rowoff & 3);
#pragma unroll
        for (int i = 0; i < 7; ++i) {
            int s = wave * 7 + i;
            const unsigned short* base;
            int row;
            if (s < 8)       { base = Ahg; row = m0 + s * 16; }
            else if (s < 16) { base = Alg; row = m0 + (s - 8) * 16; }
            else {
                int t = s - 16;          // 0..11
                int mat = t >> 2;        // 0=r,1=k,2=v
                base = Wr; row = mat * 1024 + h * 64 + (t & 3) * 16;
            }
            segsrc[i] = base + (size_t)(row + rowoff) * 1024 + q * 8;
            segdst[i] = s * 512;
        }
    }

    const int lm = lane & 15;
    const int rq = lane >> 4;
    const int qx = rq ^ (lane & 3);
    int aoff[2], boff[4];
#pragma unroll
    for (int mt = 0; mt < 2; ++mt) aoff[mt] = (wave * 32 + mt * 16 + lm) * 32 + qx * 8;
#pragma unroll
    for (int nt = 0; nt < 4; ++nt) boff[nt] = 8192 + (nt * 16 + lm) * 32 + qx * 8;

    f32x4 accr[2][4] = {}, acck[2][4] = {}, accv[2][4] = {};

    for (int kt = 0; kt < 1024; kt += 32) {
        __syncthreads();
#pragma unroll
        for (int i = 0; i < 7; ++i)
            load_lds16(segsrc[i] + kt, smem + segdst[i]);
        __syncthreads();

        f16x8 fah[2], fal[2], fbr[4], fbk[4], fbv[4];
#pragma unroll
        for (int mt = 0; mt < 2; ++mt) {
            fah[mt] = *(const f16x8*)(smem + aoff[mt]);
            fal[mt] = *(const f16x8*)(smem + 4096 + aoff[mt]);
        }
#pragma unroll
        for (int nt = 0; nt < 4; ++nt) {
            fbr[nt] = *(const f16x8*)(smem + boff[nt]);
            fbk[nt] = *(const f16x8*)(smem + 2048 + boff[nt]);
            fbv[nt] = *(const f16x8*)(smem + 4096 + boff[nt]);
        }
#pragma unroll
        for (int mt = 0; mt < 2; ++mt)
#pragma unroll
            for (int nt = 0; nt < 4; ++nt) {
                accr[mt][nt] = mfma16(fah[mt], fbr[nt], accr[mt][nt]);
                accr[mt][nt] = mfma16(fal[mt], fbr[nt], accr[mt][nt]);
                acck[mt][nt] = mfma16(fah[mt], fbk[nt], acck[mt][nt]);
                acck[mt][nt] = mfma16(fal[mt], fbk[nt], acck[mt][nt]);
                accv[mt][nt] = mfma16(fah[mt], fbv[nt], accv[mt][nt]);
                accv[mt][nt] = mfma16(fal[mt], fbv[nt], accv[mt][nt]);
            }
    }

    // ---- epilogue: sigmoid + RoPE + kv + chunk partial sums ----
    float a = a_ptr[0];
    float psum[4] = {0.f, 0.f, 0.f, 0.f};
#pragma unroll
    for (int mt = 0; mt < 2; ++mt)
#pragma unroll
        for (int p = 0; p < 2; ++p) {          // RoPE pair (p, p+2)
            int ntA = p, ntB = p + 2;
            int dA = ntA * 16 + lm, dB = ntB * 16 + lm;
#pragma unroll
            for (int r = 0; r < 4; ++r) {
                int row = wave * 32 + mt * 16 + rq * 4 + r;   // row within chunk
                int s = c * CS + row;                         // seq pos
                float csA = cosp[s * HD + dA], snA = sinp[s * HD + dA];
                float csB = cosp[s * HD + dB], snB = sinp[s * HD + dB];
                float sA = 1.f / (1.f + expf(-accr[mt][ntA][r]));
                float sB = 1.f / (1.f + expf(-accr[mt][ntB][r]));
                float rpA = sA * csA - sB * snA;
                float rpB = sB * csB + sA * snB;
                float kA = acck[mt][ntA][r], kB = acck[mt][ntB][r];
                float kpA = kA * csA - kB * snA;
                float kpB = kB * csB + kA * snB;
                float kvA = kpA * accv[mt][ntA][r];
                float kvB = kpB * accv[mt][ntB][r];
                size_t ob = ((size_t)bh * S_LEN + s) * HD;
                rP[ob + dA]  = rpA;  rP[ob + dB]  = rpB;
                kvP[ob + dA] = kvA;  kvP[ob + dB] = kvB;
                float wgt = expf(a * (float)row);
                psum[ntA] += wgt * kvA;
                psum[ntB] += wgt * kvB;
            }
        }
    // reduce over rq (lanes with same lm): xor 16, 32 preserve lm
#pragma unroll
    for (int nt = 0; nt < 4; ++nt) {
        psum[nt] += __shfl_xor(psum[nt], 16, 64);
        psum[nt] += __shfl_xor(psum[nt], 32, 64);
    }
    __syncthreads();                 // done reading smem as fp16
    float* Tf = (float*)smem;        // [4][64]
    if (rq == 0) {
#pragma unroll
        for (int nt = 0; nt < 4; ++nt) Tf[wave * 64 + nt * 16 + lm] = psum[nt];
    }
    __syncthreads();
    if (tid < 64) {
        float tot = Tf[tid] + Tf[64 + tid] + Tf[128 + tid] + Tf[192 + tid];
        Cb[((size_t)bh * NC + c) * 64 + tid] = tot;
    }
}

// ---------- K5: exclusive chunk suffix ----------
__global__ __launch_bounds__(64)
void k_chunk_suffix(const float* __restrict__ Cb, const float* __restrict__ a_ptr,
                    float* __restrict__ Sb) {
    int bh = blockIdx.x;
    int d = threadIdx.x;
    float a = a_ptr[0];
    float eaCS = expf(a * (float)CS);
    float run = 0.f;
    Sb[(size_t)(bh * NC + NC - 1) * 64 + d] = 0.f;
    for (int c = NC - 2; c >= 0; --c) {
        run = Cb[(size_t)(bh * NC + c + 1) * 64 + d] + eaCS * run;
        Sb[(size_t)(bh * NC + c) * 64 + d] = run;
    }
}

// ---------- K6: parallel in-chunk suffix scan + epilogue ----------
// Reads head-major rP/kvP; writes out as fp16 hi/lo matrices [M][1024] for GEMM2.
__global__ __launch_bounds__(256)
void k_wkv2(const float* __restrict__ rP, const float* __restrict__ kvP,
            const float* __restrict__ Sb, const float* __restrict__ a_ptr,
            const float* __restrict__ tf,
            unsigned short* __restrict__ outHi, unsigned short* __restrict__ outLo) {
    __shared__ float Tl[4][64];
    int bid = blockIdx.x;                // bh*NC + c
    int c  = bid & (NC - 1);
    int bh = bid >> 5;
    int b = bh >> 4, h = bh & 15;
    int lane = threadIdx.x & 63;
    int wave = threadIdx.x >> 6;
    float a = a_ptr[0];
    float ea = expf(a);
    float em1a = expm1f(a);
    size_t base = ((size_t)bh * S_LEN + c * CS + wave * 32) * HD + lane;

    float kvreg[32], rreg[32];
    float w = 1.f, T = 0.f;
#pragma unroll
    for (int t = 0; t < 32; ++t) {
        kvreg[t] = kvP[base + (size_t)t * HD];
        rreg[t]  = rP[base + (size_t)t * HD];
        T += w * kvreg[t];
        w *= ea;
    }
    Tl[wave][lane] = T;
    __syncthreads();

    float e32 = expf(a * 32.f);
    float S_run = Sb[(size_t)bid * 64 + lane] * expf(a * 32.f * (float)(3 - wave));
    float f = 1.f;
    for (int wp = wave + 1; wp < 4; ++wp) {
        S_run += f * Tl[wp][lane];
        f *= e32;
    }
    float tfv = tf[h * HD + lane];
#pragma unroll
    for (int t = 31; t >= 0; --t) {
        float kv = kvreg[t];
        S_run = kv + ea * S_run;
        int ig = c * CS + wave * 32 + t;
        float Z = expm1f(a * (float)(S_LEN - ig)) / em1a + 1e-8f;
        float o = rreg[t] * (tfv * kv + S_run / Z);
        HSplit s = hsplit(o);
        size_t m = (size_t)b * S_LEN + ig;
        outHi[m * HIDN + h * HD + lane] = s.hi;
        outLo[m * HIDN + h * HD + lane] = s.lo;
    }
}

// ---------- GEMM2: 2-term split-fp16 MFMA GEMM (round-5 structure) ----------
__global__ __launch_bounds__(256, 2)
void k_mfma_gemm(const unsigned short* __restrict__ Ah, const unsigned short* __restrict__ Al, int lda,
                 const unsigned short* __restrict__ Bm, int ldb,
                 float* __restrict__ C, int ldc)
{
    __shared__ unsigned short smem[12288];       // 24 KB
    const int tid  = threadIdx.x;
    const int lane = tid & 63;
    const int wave = tid >> 6;
    const int wm = wave >> 1, wn = wave & 1;
    const int m0 = blockIdx.y * 128;
    const int n0 = blockIdx.x * 128;

    const unsigned short* gsrc;
    size_t gstep;
    int segbase;
    {
        int rowoff = lane >> 2;
        int q = (lane & 3) ^ ((lane >> 2) & 3);
        if (wave < 2) {
            const unsigned short* base = (wave == 0) ? Ah : Al;
            gsrc = base + (size_t)(m0 + rowoff) * lda + q * 8;
            gstep = (size_t)16 * lda;
            segbase = wave * 8;
        } else {
            gsrc = Bm + (size_t)(n0 + (wave - 2) * 64 + rowoff) * ldb + q * 8;
            gstep = (size_t)16 * ldb;
            segbase = 16 + (wave - 2) * 4;
        }
    }

    const int lm = lane & 15;
    const int qx = (lane >> 4) ^ (lane & 3);
    int aoff[4], boff[4];
#pragma unroll
    for (int t = 0; t < 4; ++t) {
        aoff[t] = (wm * 64 + t * 16 + lm) * 32 + qx * 8;
        boff[t] = 8192 + (wn * 64 + t * 16 + lm) * 32 + qx * 8;
    }

    f32x4 acc[4][4] = {};

    for (int kt = 0; kt < 1024; kt += 32) {
        __syncthreads();
        const unsigned short* g = gsrc + kt;
        if (wave < 2) {
#pragma unroll
            for (int i = 0; i < 8; ++i)
                load_lds16(g + (size_t)i * gstep, smem + (segbase + i) * 512);
        } else {
#pragma unroll
            for (int i = 0; i < 4; ++i)
                load_lds16(g + (size_t)i * gstep, smem + (segbase + i) * 512);
        }
        __syncthreads();

        f16x8 fah[4], fal[4], fb[4];
#pragma unroll
        for (int t = 0; t < 4; ++t) {
            fah[t] = *(const f16x8*)(smem + aoff[t]);
            fal[t] = *(const f16x8*)(smem + 4096 + aoff[t]);
            fb[t]  = *(const f16x8*)(smem + boff[t]);
        }
#pragma unroll
        for (int mt = 0; mt < 4; ++mt)
#pragma unroll
            for (int nt = 0; nt < 4; ++nt) {
                acc[mt][nt] = mfma16(fah[mt], fb[nt], acc[mt][nt]);
                acc[mt][nt] = mfma16(fal[mt], fb[nt], acc[mt][nt]);
            }
    }

    const int rq = lane >> 4;
#pragma unroll
    for (int mt = 0; mt < 4; ++mt)
#pragma unroll
        for (int nt = 0; nt < 4; ++nt) {
            int col = n0 + wn * 64 + nt * 16 + lm;
#pragma unroll
            for (int r = 0; r < 4; ++r) {
                int row = m0 + wm * 64 + mt * 16 + rq * 4 + r;
                C[(size_t)row * ldc + col] = acc[mt][nt][r];
            }
        }
}

extern "C" void kernel_launch(void* const* d_in, const int* in_sizes, int n_in,
                              void* d_out, int out_size, void* d_ws, size_t ws_size,
                              hipStream_t stream) {
    const float* hs    = (const float*)d_in[0];
    const float* cosp  = (const float*)d_in[1];
    const float* sinp  = (const float*)d_in[2];
    const float* W_rkv = (const float*)d_in[3];
    const float* W_o   = (const float*)d_in[4];
    const float* td    = (const float*)d_in[5];
    const float* tf    = (const float*)d_in[6];
    const float* tm    = (const float*)d_in[7];
    float* out = (float*)d_out;

    char* w = (char*)d_ws;
    float*          rP    = (float*)w;                            // 32 MiB
    float*          kvP   = (float*)(w + 33554432);               // 32 MiB
    unsigned short* Ah    = (unsigned short*)(w + 67108864);      // 16 MiB
    unsigned short* Al    = (unsigned short*)(w + 83886080);      // 16 MiB
    unsigned short* Wrh   = (unsigned short*)(w + 100663296);     // 6 MiB
    unsigned short* Woh   = (unsigned short*)(w + 106954752);     // 2 MiB
    unsigned short* outHi = (unsigned short*)(w + 109051904);     // 16 MiB
    unsigned short* outLo = (unsigned short*)(w + 125829120);     // 16 MiB
    float*          Cb    = (float*)(w + 141557760);              // 256 KiB
    float*          Sb    = (float*)(w + 141819904);              // 256 KiB
    float*          a_ptr = (float*)(w + 142082048);

    k_avg_decay<<<1, 64, 0, stream>>>(td, a_ptr);

    k_split_mix<<<(M_TOTAL * HIDN / 4) / 256, 256, 0, stream>>>(hs, tm, Ah, Al);
    k_split_w<<<(N_RKV * HIDN / 4) / 256, 256, 0, stream>>>(W_rkv, Wrh);
    k_split_w<<<(HIDN * HIDN / 4) / 256, 256, 0, stream>>>(W_o, Woh);

    dim3 g1(NH, M_TOTAL / 128);   // (16 heads, 64 chunks)
    k_gemm1_fused<<<g1, 256, 0, stream>>>(Ah, Al, Wrh, cosp, sinp, a_ptr, rP, kvP, Cb);

    k_chunk_suffix<<<BATCH * NH, 64, 0, stream>>>(Cb, a_ptr, Sb);
    k_wkv2<<<BATCH * NH * NC, 256, 0, stream>>>(rP, kvP, Sb, a_ptr, tf, outHi, outLo);

    dim3 g2(HIDN / 128, M_TOTAL / 128);
    k_mfma_gemm<<<g2, 256, 0, stream>>>(outHi, outLo, HIDN, Woh, HIDN, out, HIDN);
}

// Round 7
// 307.216 us; speedup vs baseline: 4.3070x; 1.0056x over previous
//
#include <hip/hip_runtime.h>
#include <math.h>

#define S_LEN 4096
#define HIDN  1024
#define NH    16
#define HD    64
#define BATCH 2
#define M_TOTAL (BATCH * S_LEN)   // 8192
#define N_RKV   (3 * HIDN)        // 3072
#define CS 128
#define NC (S_LEN / CS)           // 32

typedef __attribute__((ext_vector_type(8))) _Float16 f16x8;
typedef __attribute__((ext_vector_type(4))) float f32x4;
typedef __attribute__((ext_vector_type(4))) unsigned short u16x4;

// ---------- fp16 convert ----------
__device__ __forceinline__ unsigned short f2h(float x) {
    _Float16 h = (_Float16)x;
    return *(unsigned short*)&h;
}

// ---------- async global->LDS, 16B per lane ----------
__device__ __forceinline__ void load_lds16(const void* g, void* l) {
    __builtin_amdgcn_global_load_lds((const __attribute__((address_space(1))) void*)g,
                                     (__attribute__((address_space(3))) void*)l, 16, 0, 0);
}

// ---------- K0: a = mean(exp(time_decay)) ----------
__global__ void k_avg_decay(const float* __restrict__ td, float* __restrict__ a_out) {
    int t = threadIdx.x;
    double acc = 0.0;
    for (int i = t; i < NH * HD; i += 64) acc += exp((double)td[i]);
    for (int off = 32; off > 0; off >>= 1) acc += __shfl_down(acc, off, 64);
    if (t == 0) a_out[0] = (float)(acc / (double)(NH * HD));
}

// ---------- K1a: mixed = hs*tm + shift(hs)*(1-tm) -> fp16 ----------
__global__ __launch_bounds__(256)
void k_split_mix(const float* __restrict__ hs, const float* __restrict__ tm,
                 unsigned short* __restrict__ Ah) {
    int g = blockIdx.x * 256 + threadIdx.x;      // over M_TOTAL * (HIDN/4)
    int kc = (g & 255) * 4;
    int m = g >> 8;
    float4 cur = *(const float4*)&hs[(size_t)m * HIDN + kc];
    float4 t4  = *(const float4*)&tm[kc];
    float4 prev = make_float4(0.f, 0.f, 0.f, 0.f);
    if (m & (S_LEN - 1)) prev = *(const float4*)&hs[(size_t)(m - 1) * HIDN + kc];
    u16x4 h;
    h.x = f2h(cur.x * t4.x + prev.x * (1.f - t4.x));
    h.y = f2h(cur.y * t4.y + prev.y * (1.f - t4.y));
    h.z = f2h(cur.z * t4.z + prev.z * (1.f - t4.z));
    h.w = f2h(cur.w * t4.w + prev.w * (1.f - t4.w));
    *(u16x4*)&Ah[(size_t)m * HIDN + kc] = h;
}

// ---------- K1b: flat fp32 -> fp16 (weights) ----------
__global__ __launch_bounds__(256)
void k_split_w(const float* __restrict__ W, unsigned short* __restrict__ Wh) {
    int g = blockIdx.x * 256 + threadIdx.x;
    size_t o = (size_t)g * 4;
    float4 v = *(const float4*)&W[o];
    u16x4 h;
    h.x = f2h(v.x); h.y = f2h(v.y); h.z = f2h(v.z); h.w = f2h(v.w);
    *(u16x4*)&Wh[o] = h;
}

__device__ __forceinline__ f32x4 mfma16(f16x8 a, f16x8 b, f32x4 c) {
    return __builtin_amdgcn_mfma_f32_16x16x32_f16(a, b, c, 0, 0, 0);
}

// ---------- K2: fused GEMM1 (single-term fp16) + sigmoid/RoPE/kv + chunk sums ----------
// Block: one head x one 128-row chunk. 4 waves x 32 rows. LDS 20KB:
// A[0,4096) Br[4096,6144) Bk[6144,8192) Bv[8192,10240) (u16 elems).
__global__ __launch_bounds__(256)
void k_gemm1_fused(const unsigned short* __restrict__ Ahg,
                   const unsigned short* __restrict__ Wr,
                   const float* __restrict__ cosp, const float* __restrict__ sinp,
                   const float* __restrict__ a_ptr,
                   float* __restrict__ rP, float* __restrict__ kvP, float* __restrict__ Cb)
{
    __shared__ unsigned short smem[10240];   // 20 KB
    const int tid  = threadIdx.x;
    const int lane = tid & 63;
    const int wave = tid >> 6;
    const int h  = blockIdx.x;          // 0..15
    const int mc = blockIdx.y;          // 0..63
    const int m0 = mc * 128;
    const int b  = mc >> 5;
    const int c  = mc & 31;
    const int bh = b * NH + h;

    // staging: 20 segments (16 rows x 32 k each); wave handles segs [5w, 5w+5)
    const unsigned short* segsrc[5];
    int segdst[5];
    {
        int rowoff = lane >> 2;
        int q = (lane & 3) ^ (rowoff & 3);
#pragma unroll
        for (int i = 0; i < 5; ++i) {
            int s = wave * 5 + i;
            const unsigned short* base;
            int row;
            if (s < 8) { base = Ahg; row = m0 + s * 16; }
            else {
                int t = s - 8;           // 0..11
                int mat = t >> 2;        // 0=r,1=k,2=v
                base = Wr; row = mat * 1024 + h * 64 + (t & 3) * 16;
            }
            segsrc[i] = base + (size_t)(row + rowoff) * 1024 + q * 8;
            segdst[i] = s * 512;
        }
    }

    const int lm = lane & 15;
    const int rq = lane >> 4;
    const int qx = rq ^ (lane & 3);
    int aoff[2], boff[4];
#pragma unroll
    for (int mt = 0; mt < 2; ++mt) aoff[mt] = (wave * 32 + mt * 16 + lm) * 32 + qx * 8;
#pragma unroll
    for (int nt = 0; nt < 4; ++nt) boff[nt] = 4096 + (nt * 16 + lm) * 32 + qx * 8;

    f32x4 accr[2][4] = {}, acck[2][4] = {}, accv[2][4] = {};

    for (int kt = 0; kt < 1024; kt += 32) {
        __syncthreads();
#pragma unroll
        for (int i = 0; i < 5; ++i)
            load_lds16(segsrc[i] + kt, smem + segdst[i]);
        __syncthreads();

        f16x8 fah[2], fbr[4], fbk[4], fbv[4];
#pragma unroll
        for (int mt = 0; mt < 2; ++mt) fah[mt] = *(const f16x8*)(smem + aoff[mt]);
#pragma unroll
        for (int nt = 0; nt < 4; ++nt) {
            fbr[nt] = *(const f16x8*)(smem + boff[nt]);
            fbk[nt] = *(const f16x8*)(smem + 2048 + boff[nt]);
            fbv[nt] = *(const f16x8*)(smem + 4096 + boff[nt]);
        }
#pragma unroll
        for (int mt = 0; mt < 2; ++mt)
#pragma unroll
            for (int nt = 0; nt < 4; ++nt) {
                accr[mt][nt] = mfma16(fah[mt], fbr[nt], accr[mt][nt]);
                acck[mt][nt] = mfma16(fah[mt], fbk[nt], acck[mt][nt]);
                accv[mt][nt] = mfma16(fah[mt], fbv[nt], accv[mt][nt]);
            }
    }

    // ---- epilogue: sigmoid + RoPE + kv + chunk partial sums ----
    float a = a_ptr[0];
    float psum[4] = {0.f, 0.f, 0.f, 0.f};
#pragma unroll
    for (int mt = 0; mt < 2; ++mt)
#pragma unroll
        for (int p = 0; p < 2; ++p) {          // RoPE pair (p, p+2)
            int ntA = p, ntB = p + 2;
            int dA = ntA * 16 + lm, dB = ntB * 16 + lm;
#pragma unroll
            for (int r = 0; r < 4; ++r) {
                int row = wave * 32 + mt * 16 + rq * 4 + r;   // row within chunk
                int s = c * CS + row;                         // seq pos
                float csA = cosp[s * HD + dA], snA = sinp[s * HD + dA];
                float csB = cosp[s * HD + dB], snB = sinp[s * HD + dB];
                float sA = 1.f / (1.f + expf(-accr[mt][ntA][r]));
                float sB = 1.f / (1.f + expf(-accr[mt][ntB][r]));
                float rpA = sA * csA - sB * snA;
                float rpB = sB * csB + sA * snB;
                float kA = acck[mt][ntA][r], kB = acck[mt][ntB][r];
                float kpA = kA * csA - kB * snA;
                float kpB = kB * csB + kA * snB;
                float kvA = kpA * accv[mt][ntA][r];
                float kvB = kpB * accv[mt][ntB][r];
                size_t ob = ((size_t)bh * S_LEN + s) * HD;
                rP[ob + dA]  = rpA;  rP[ob + dB]  = rpB;
                kvP[ob + dA] = kvA;  kvP[ob + dB] = kvB;
                float wgt = expf(a * (float)row);
                psum[ntA] += wgt * kvA;
                psum[ntB] += wgt * kvB;
            }
        }
#pragma unroll
    for (int nt = 0; nt < 4; ++nt) {
        psum[nt] += __shfl_xor(psum[nt], 16, 64);
        psum[nt] += __shfl_xor(psum[nt], 32, 64);
    }
    __syncthreads();
    float* Tf = (float*)smem;        // [4][64]
    if (rq == 0) {
#pragma unroll
        for (int nt = 0; nt < 4; ++nt) Tf[wave * 64 + nt * 16 + lm] = psum[nt];
    }
    __syncthreads();
    if (tid < 64) {
        float tot = Tf[tid] + Tf[64 + tid] + Tf[128 + tid] + Tf[192 + tid];
        Cb[((size_t)bh * NC + c) * 64 + tid] = tot;
    }
}

// ---------- K5: exclusive chunk suffix ----------
__global__ __launch_bounds__(64)
void k_chunk_suffix(const float* __restrict__ Cb, const float* __restrict__ a_ptr,
                    float* __restrict__ Sb) {
    int bh = blockIdx.x;
    int d = threadIdx.x;
    float a = a_ptr[0];
    float eaCS = expf(a * (float)CS);
    float run = 0.f;
    Sb[(size_t)(bh * NC + NC - 1) * 64 + d] = 0.f;
    for (int c = NC - 2; c >= 0; --c) {
        run = Cb[(size_t)(bh * NC + c + 1) * 64 + d] + eaCS * run;
        Sb[(size_t)(bh * NC + c) * 64 + d] = run;
    }
}

// ---------- K6: parallel in-chunk suffix scan + epilogue (fp16 out) ----------
__global__ __launch_bounds__(256)
void k_wkv2(const float* __restrict__ rP, const float* __restrict__ kvP,
            const float* __restrict__ Sb, const float* __restrict__ a_ptr,
            const float* __restrict__ tf,
            unsigned short* __restrict__ outH) {
    __shared__ float Tl[4][64];
    int bid = blockIdx.x;                // bh*NC + c
    int c  = bid & (NC - 1);
    int bh = bid >> 5;
    int b = bh >> 4, h = bh & 15;
    int lane = threadIdx.x & 63;
    int wave = threadIdx.x >> 6;
    float a = a_ptr[0];
    float ea = expf(a);
    float em1a = expm1f(a);
    size_t base = ((size_t)bh * S_LEN + c * CS + wave * 32) * HD + lane;

    float kvreg[32], rreg[32];
    float w = 1.f, T = 0.f;
#pragma unroll
    for (int t = 0; t < 32; ++t) {
        kvreg[t] = kvP[base + (size_t)t * HD];
        rreg[t]  = rP[base + (size_t)t * HD];
        T += w * kvreg[t];
        w *= ea;
    }
    Tl[wave][lane] = T;
    __syncthreads();

    float e32 = expf(a * 32.f);
    float S_run = Sb[(size_t)bid * 64 + lane] * expf(a * 32.f * (float)(3 - wave));
    float f = 1.f;
    for (int wp = wave + 1; wp < 4; ++wp) {
        S_run += f * Tl[wp][lane];
        f *= e32;
    }
    float tfv = tf[h * HD + lane];
#pragma unroll
    for (int t = 31; t >= 0; --t) {
        float kv = kvreg[t];
        S_run = kv + ea * S_run;
        int ig = c * CS + wave * 32 + t;
        float Z = expm1f(a * (float)(S_LEN - ig)) / em1a + 1e-8f;
        float o = rreg[t] * (tfv * kv + S_run / Z);
        size_t m = (size_t)b * S_LEN + ig;
        outH[m * HIDN + h * HD + lane] = f2h(o);
    }
}

// ---------- GEMM2: single-term fp16 MFMA GEMM ----------
// 128x128 tile, BK=32, 4 waves 2x2. LDS 16KB: A[0,4096) B[4096,8192).
__global__ __launch_bounds__(256, 2)
void k_mfma_gemm(const unsigned short* __restrict__ Ah, int lda,
                 const unsigned short* __restrict__ Bm, int ldb,
                 float* __restrict__ C, int ldc)
{
    __shared__ unsigned short smem[8192];        // 16 KB
    const int tid  = threadIdx.x;
    const int lane = tid & 63;
    const int wave = tid >> 6;
    const int wm = wave >> 1, wn = wave & 1;
    const int m0 = blockIdx.y * 128;
    const int n0 = blockIdx.x * 128;

    // staging: 16 segs; wave handles segs [4w, 4w+4)
    const unsigned short* segsrc[4];
    int segdst[4];
    {
        int rowoff = lane >> 2;
        int q = (lane & 3) ^ (rowoff & 3);
#pragma unroll
        for (int i = 0; i < 4; ++i) {
            int s = wave * 4 + i;
            const unsigned short* base = (s < 8) ? Ah : Bm;
            int ld = (s < 8) ? lda : ldb;
            int row = (s < 8) ? (m0 + s * 16) : (n0 + (s - 8) * 16);
            segsrc[i] = base + (size_t)(row + rowoff) * ld + q * 8;
            segdst[i] = s * 512;
        }
    }

    const int lm = lane & 15;
    const int qx = (lane >> 4) ^ (lane & 3);
    int aoff[4], boff[4];
#pragma unroll
    for (int t = 0; t < 4; ++t) {
        aoff[t] = (wm * 64 + t * 16 + lm) * 32 + qx * 8;
        boff[t] = 4096 + (wn * 64 + t * 16 + lm) * 32 + qx * 8;
    }

    f32x4 acc[4][4] = {};

    for (int kt = 0; kt < 1024; kt += 32) {
        __syncthreads();
#pragma unroll
        for (int i = 0; i < 4; ++i)
            load_lds16(segsrc[i] + kt, smem + segdst[i]);
        __syncthreads();

        f16x8 fah[4], fb[4];
#pragma unroll
        for (int t = 0; t < 4; ++t) {
            fah[t] = *(const f16x8*)(smem + aoff[t]);
            fb[t]  = *(const f16x8*)(smem + boff[t]);
        }
#pragma unroll
        for (int mt = 0; mt < 4; ++mt)
#pragma unroll
            for (int nt = 0; nt < 4; ++nt)
                acc[mt][nt] = mfma16(fah[mt], fb[nt], acc[mt][nt]);
    }

    const int rq = lane >> 4;
#pragma unroll
    for (int mt = 0; mt < 4; ++mt)
#pragma unroll
        for (int nt = 0; nt < 4; ++nt) {
            int col = n0 + wn * 64 + nt * 16 + lm;
#pragma unroll
            for (int r = 0; r < 4; ++r) {
                int row = m0 + wm * 64 + mt * 16 + rq * 4 + r;
                C[(size_t)row * ldc + col] = acc[mt][nt][r];
            }
        }
}

extern "C" void kernel_launch(void* const* d_in, const int* in_sizes, int n_in,
                              void* d_out, int out_size, void* d_ws, size_t ws_size,
                              hipStream_t stream) {
    const float* hs    = (const float*)d_in[0];
    const float* cosp  = (const float*)d_in[1];
    const float* sinp  = (const float*)d_in[2];
    const float* W_rkv = (const float*)d_in[3];
    const float* W_o   = (const float*)d_in[4];
    const float* td    = (const float*)d_in[5];
    const float* tf    = (const float*)d_in[6];
    const float* tm    = (const float*)d_in[7];
    float* out = (float*)d_out;

    char* w = (char*)d_ws;
    float*          rP    = (float*)w;                            // 32 MiB
    float*          kvP   = (float*)(w + 33554432);               // 32 MiB
    unsigned short* Ah    = (unsigned short*)(w + 67108864);      // 16 MiB
    unsigned short* Wrh   = (unsigned short*)(w + 83886080);      // 6 MiB
    unsigned short* Woh   = (unsigned short*)(w + 90177536);      // 2 MiB
    unsigned short* outH  = (unsigned short*)(w + 92274688);      // 16 MiB
    float*          Cb    = (float*)(w + 109051904);              // 256 KiB
    float*          Sb    = (float*)(w + 109314048);              // 256 KiB
    float*          a_ptr = (float*)(w + 109576192);

    k_avg_decay<<<1, 64, 0, stream>>>(td, a_ptr);

    k_split_mix<<<(M_TOTAL * HIDN / 4) / 256, 256, 0, stream>>>(hs, tm, Ah);
    k_split_w<<<(N_RKV * HIDN / 4) / 256, 256, 0, stream>>>(W_rkv, Wrh);
    k_split_w<<<(HIDN * HIDN / 4) / 256, 256, 0, stream>>>(W_o, Woh);

    dim3 g1(NH, M_TOTAL / 128);   // (16 heads, 64 chunks)
    k_gemm1_fused<<<g1, 256, 0, stream>>>(Ah, Wrh, cosp, sinp, a_ptr, rP, kvP, Cb);

    k_chunk_suffix<<<BATCH * NH, 64, 0, stream>>>(Cb, a_ptr, Sb);
    k_wkv2<<<BATCH * NH * NC, 256, 0, stream>>>(rP, kvP, Sb, a_ptr, tf, outH);

    dim3 g2(HIDN / 128, M_TOTAL / 128);
    k_mfma_gemm<<<g2, 256, 0, stream>>>(outH, HIDN, Woh, HIDN, out, HIDN);
}

// Round 8
// 264.870 us; speedup vs baseline: 4.9956x; 1.1599x over previous
//
#include <hip/hip_runtime.h>
#include <math.h>

#define S_LEN 4096
#define HIDN  1024
#define NH    16
#define HD    64
#define BATCH 2
#define M_TOTAL (BATCH * S_LEN)   // 8192
#define N_RKV   (3 * HIDN)        // 3072
#define CS 128
#define NC (S_LEN / CS)           // 32

typedef __attribute__((ext_vector_type(8))) _Float16 f16x8;
typedef __attribute__((ext_vector_type(4))) float f32x4;
typedef __attribute__((ext_vector_type(4))) unsigned short u16x4;

// ---------- fp16 convert ----------
__device__ __forceinline__ unsigned short f2h(float x) {
    _Float16 h = (_Float16)x;
    return *(unsigned short*)&h;
}
__device__ __forceinline__ float h2f(unsigned short b) {
    _Float16 h = *(_Float16*)&b;
    return (float)h;
}

// ---------- async global->LDS, 16B per lane ----------
__device__ __forceinline__ void load_lds16(const void* g, void* l) {
    __builtin_amdgcn_global_load_lds((const __attribute__((address_space(1))) void*)g,
                                     (__attribute__((address_space(3))) void*)l, 16, 0, 0);
}

// ---------- K0: a = mean(exp(time_decay)) ----------
__global__ void k_avg_decay(const float* __restrict__ td, float* __restrict__ a_out) {
    int t = threadIdx.x;
    double acc = 0.0;
    for (int i = t; i < NH * HD; i += 64) acc += exp((double)td[i]);
    for (int off = 32; off > 0; off >>= 1) acc += __shfl_down(acc, off, 64);
    if (t == 0) a_out[0] = (float)(acc / (double)(NH * HD));
}

// ---------- K1a: mixed = hs*tm + shift(hs)*(1-tm) -> fp16 ----------
__global__ __launch_bounds__(256)
void k_split_mix(const float* __restrict__ hs, const float* __restrict__ tm,
                 unsigned short* __restrict__ Ah) {
    int g = blockIdx.x * 256 + threadIdx.x;      // over M_TOTAL * (HIDN/4)
    int kc = (g & 255) * 4;
    int m = g >> 8;
    float4 cur = *(const float4*)&hs[(size_t)m * HIDN + kc];
    float4 t4  = *(const float4*)&tm[kc];
    float4 prev = make_float4(0.f, 0.f, 0.f, 0.f);
    if (m & (S_LEN - 1)) prev = *(const float4*)&hs[(size_t)(m - 1) * HIDN + kc];
    u16x4 h;
    h.x = f2h(cur.x * t4.x + prev.x * (1.f - t4.x));
    h.y = f2h(cur.y * t4.y + prev.y * (1.f - t4.y));
    h.z = f2h(cur.z * t4.z + prev.z * (1.f - t4.z));
    h.w = f2h(cur.w * t4.w + prev.w * (1.f - t4.w));
    *(u16x4*)&Ah[(size_t)m * HIDN + kc] = h;
}

// ---------- K1b: flat fp32 -> fp16 (weights) ----------
__global__ __launch_bounds__(256)
void k_split_w(const float* __restrict__ W, unsigned short* __restrict__ Wh) {
    int g = blockIdx.x * 256 + threadIdx.x;
    size_t o = (size_t)g * 4;
    float4 v = *(const float4*)&W[o];
    u16x4 h;
    h.x = f2h(v.x); h.y = f2h(v.y); h.z = f2h(v.z); h.w = f2h(v.w);
    *(u16x4*)&Wh[o] = h;
}

__device__ __forceinline__ f32x4 mfma16(f16x8 a, f16x8 b, f32x4 c) {
    return __builtin_amdgcn_mfma_f32_16x16x32_f16(a, b, c, 0, 0, 0);
}

// ---------- K2: fused GEMM1 v2 ----------
// Block = (head h, 128-row chunk). 192 threads = 3 waves; wave w computes
// matrix w (0=r,1=k,2=v): full 128x64 tile = 8 m-tiles x 4 n-tiles, single-term
// fp16 MFMA. Double-buffered global_load_lds staging (2 x 20KB). Epilogue
// exchanges acc planes via LDS in 4 row-groups of 32, applies sigmoid+RoPE+kv,
// writes fp16 rP/kvP and fp32 chunk sums Cb.
__global__ __launch_bounds__(192, 2)
void k_gemm1_fused(const unsigned short* __restrict__ Ahg,
                   const unsigned short* __restrict__ Wr,
                   const float* __restrict__ cosp, const float* __restrict__ sinp,
                   const float* __restrict__ a_ptr,
                   unsigned short* __restrict__ rP, unsigned short* __restrict__ kvP,
                   float* __restrict__ Cb)
{
    __shared__ unsigned short smem[20480];   // 40 KB: two 10240-elem staging buffers
    const int tid  = threadIdx.x;
    const int lane = tid & 63;
    const int wave = tid >> 6;          // 0..2 = matrix r/k/v
    const int h  = blockIdx.x;          // 0..15
    const int mc = blockIdx.y;          // 0..63
    const int m0 = mc * 128;
    const int b  = mc >> 5;
    const int c  = mc & 31;
    const int bh = b * NH + h;

    // staging: 20 segments (16 rows x 32 k, 1KB each); wave handles s = wave+3i
    const unsigned short* segsrc[7];
    int segdst[7];
    {
        int rowoff = lane >> 2;
        int q = (lane & 3) ^ (rowoff & 3);
#pragma unroll
        for (int i = 0; i < 7; ++i) {
            int s = wave + 3 * i;
            if (s < 20) {
                const unsigned short* base;
                int row;
                if (s < 8) { base = Ahg; row = m0 + s * 16; }
                else {
                    int t = s - 8;               // 0..11
                    base = Wr;
                    row = (t >> 2) * 1024 + h * 64 + (t & 3) * 16;
                }
                segsrc[i] = base + (size_t)(row + rowoff) * 1024 + q * 8;
                segdst[i] = (s < 8) ? s * 512 : 4096 + (s - 8) * 512;
            }
        }
    }

    const int lm = lane & 15;
    const int rq = lane >> 4;
    const int qx = rq ^ (lane & 3);

    f32x4 acc[8][4] = {};

    // prologue: stage kt=0 into buffer 0
#pragma unroll
    for (int i = 0; i < 7; ++i)
        if (wave + 3 * i < 20) load_lds16(segsrc[i], smem + segdst[i]);

    int p = 0;
    for (int kt = 0; kt < 1024; kt += 32) {
        __syncthreads();                 // buffer p staged; old readers done
        if (kt + 32 < 1024) {
            int np = p ^ 1;
#pragma unroll
            for (int i = 0; i < 7; ++i)
                if (wave + 3 * i < 20)
                    load_lds16(segsrc[i] + kt + 32, smem + np * 10240 + segdst[i]);
        }
        const unsigned short* sb = smem + p * 10240;
        f16x8 fa[8], fb[4];
#pragma unroll
        for (int mt = 0; mt < 8; ++mt)
            fa[mt] = *(const f16x8*)(sb + (mt * 16 + lm) * 32 + qx * 8);
#pragma unroll
        for (int nt = 0; nt < 4; ++nt)
            fb[nt] = *(const f16x8*)(sb + 4096 + (wave * 64 + nt * 16 + lm) * 32 + qx * 8);
#pragma unroll
        for (int mt = 0; mt < 8; ++mt)
#pragma unroll
            for (int nt = 0; nt < 4; ++nt)
                acc[mt][nt] = mfma16(fa[mt], fb[nt], acc[mt][nt]);
        p ^= 1;
    }

    // ---- epilogue: 4 row-groups of 32; LDS plane exchange [3][32][64] fp32 ----
    float a = a_ptr[0];
    float psum = 0.f;
    const int d = lane;                  // 0..63
    float* Lf = (float*)smem;            // 24 KB region
#pragma unroll
    for (int g = 0; g < 4; ++g) {
        __syncthreads();
#pragma unroll
        for (int mt2 = 0; mt2 < 2; ++mt2) {
            int mt = 2 * g + mt2;
#pragma unroll
            for (int nt = 0; nt < 4; ++nt)
#pragma unroll
                for (int r = 0; r < 4; ++r) {
                    int rl = mt2 * 16 + rq * 4 + r;          // 0..31
                    Lf[(wave * 32 + rl) * 64 + nt * 16 + lm] = acc[mt][nt][r];
                }
        }
        __syncthreads();
        for (int row = wave; row < 32; row += 3) {
            int s = c * CS + g * 32 + row;
            int dp = d ^ 32;
            float r_ = Lf[row * 64 + d];
            float rp = Lf[row * 64 + dp];
            float k_ = Lf[(32 + row) * 64 + d];
            float kp = Lf[(32 + row) * 64 + dp];
            float v_ = Lf[(64 + row) * 64 + d];
            float cs = cosp[s * HD + d], sn = sinp[s * HD + d];
            float sgn = (d < 32) ? -1.f : 1.f;
            float sig  = 1.f / (1.f + expf(-r_));
            float sigp = 1.f / (1.f + expf(-rp));
            float rr = sig * cs + sgn * sigp * sn;
            float kk = k_ * cs + sgn * kp * sn;
            float kv = kk * v_;
            size_t ob = ((size_t)bh * S_LEN + s) * HD + d;
            rP[ob]  = f2h(rr);
            kvP[ob] = f2h(kv);
            psum += expf(a * (float)(g * 32 + row)) * kv;
        }
    }
    __syncthreads();
    Lf[wave * 64 + d] = psum;            // (wave,d) unique over 192 threads
    __syncthreads();
    if (tid < 64)
        Cb[((size_t)bh * NC + c) * 64 + tid] = Lf[tid] + Lf[64 + tid] + Lf[128 + tid];
}

// ---------- K5: exclusive chunk suffix ----------
__global__ __launch_bounds__(64)
void k_chunk_suffix(const float* __restrict__ Cb, const float* __restrict__ a_ptr,
                    float* __restrict__ Sb) {
    int bh = blockIdx.x;
    int d = threadIdx.x;
    float a = a_ptr[0];
    float eaCS = expf(a * (float)CS);
    float run = 0.f;
    Sb[(size_t)(bh * NC + NC - 1) * 64 + d] = 0.f;
    for (int c = NC - 2; c >= 0; --c) {
        run = Cb[(size_t)(bh * NC + c + 1) * 64 + d] + eaCS * run;
        Sb[(size_t)(bh * NC + c) * 64 + d] = run;
    }
}

// ---------- K6: parallel in-chunk suffix scan + epilogue (fp16 in, fp16 out) ----------
__global__ __launch_bounds__(256)
void k_wkv2(const unsigned short* __restrict__ rP, const unsigned short* __restrict__ kvP,
            const float* __restrict__ Sb, const float* __restrict__ a_ptr,
            const float* __restrict__ tf,
            unsigned short* __restrict__ outH) {
    __shared__ float Tl[4][64];
    int bid = blockIdx.x;                // bh*NC + c
    int c  = bid & (NC - 1);
    int bh = bid >> 5;
    int b = bh >> 4, h = bh & 15;
    int lane = threadIdx.x & 63;
    int wave = threadIdx.x >> 6;
    float a = a_ptr[0];
    float ea = expf(a);
    float em1a = expm1f(a);
    size_t base = ((size_t)bh * S_LEN + c * CS + wave * 32) * HD + lane;

    float kvreg[32], rreg[32];
    float w = 1.f, T = 0.f;
#pragma unroll
    for (int t = 0; t < 32; ++t) {
        kvreg[t] = h2f(kvP[base + (size_t)t * HD]);
        rreg[t]  = h2f(rP[base + (size_t)t * HD]);
        T += w * kvreg[t];
        w *= ea;
    }
    Tl[wave][lane] = T;
    __syncthreads();

    float e32 = expf(a * 32.f);
    float S_run = Sb[(size_t)bid * 64 + lane] * expf(a * 32.f * (float)(3 - wave));
    float f = 1.f;
    for (int wp = wave + 1; wp < 4; ++wp) {
        S_run += f * Tl[wp][lane];
        f *= e32;
    }
    float tfv = tf[h * HD + lane];
#pragma unroll
    for (int t = 31; t >= 0; --t) {
        float kv = kvreg[t];
        S_run = kv + ea * S_run;
        int ig = c * CS + wave * 32 + t;
        float Z = expm1f(a * (float)(S_LEN - ig)) / em1a + 1e-8f;
        float o = rreg[t] * (tfv * kv + S_run / Z);
        size_t m = (size_t)b * S_LEN + ig;
        outH[m * HIDN + h * HD + lane] = f2h(o);
    }
}

// ---------- GEMM2: single-term fp16 MFMA GEMM ----------
__global__ __launch_bounds__(256, 2)
void k_mfma_gemm(const unsigned short* __restrict__ Ah, int lda,
                 const unsigned short* __restrict__ Bm, int ldb,
                 float* __restrict__ C, int ldc)
{
    __shared__ unsigned short smem[8192];        // 16 KB
    const int tid  = threadIdx.x;
    const int lane = tid & 63;
    const int wave = tid >> 6;
    const int wm = wave >> 1, wn = wave & 1;
    const int m0 = blockIdx.y * 128;
    const int n0 = blockIdx.x * 128;

    const unsigned short* segsrc[4];
    int segdst[4];
    {
        int rowoff = lane >> 2;
        int q = (lane & 3) ^ (rowoff & 3);
#pragma unroll
        for (int i = 0; i < 4; ++i) {
            int s = wave * 4 + i;
            const unsigned short* base = (s < 8) ? Ah : Bm;
            int ld = (s < 8) ? lda : ldb;
            int row = (s < 8) ? (m0 + s * 16) : (n0 + (s - 8) * 16);
            segsrc[i] = base + (size_t)(row + rowoff) * ld + q * 8;
            segdst[i] = s * 512;
        }
    }

    const int lm = lane & 15;
    const int qx = (lane >> 4) ^ (lane & 3);
    int aoff[4], boff[4];
#pragma unroll
    for (int t = 0; t < 4; ++t) {
        aoff[t] = (wm * 64 + t * 16 + lm) * 32 + qx * 8;
        boff[t] = 4096 + (wn * 64 + t * 16 + lm) * 32 + qx * 8;
    }

    f32x4 acc[4][4] = {};

    for (int kt = 0; kt < 1024; kt += 32) {
        __syncthreads();
#pragma unroll
        for (int i = 0; i < 4; ++i)
            load_lds16(segsrc[i] + kt, smem + segdst[i]);
        __syncthreads();

        f16x8 fah[4], fb[4];
#pragma unroll
        for (int t = 0; t < 4; ++t) {
            fah[t] = *(const f16x8*)(smem + aoff[t]);
            fb[t]  = *(const f16x8*)(smem + boff[t]);
        }
#pragma unroll
        for (int mt = 0; mt < 4; ++mt)
#pragma unroll
            for (int nt = 0; nt < 4; ++nt)
                acc[mt][nt] = mfma16(fah[mt], fb[nt], acc[mt][nt]);
    }

    const int rq = lane >> 4;
#pragma unroll
    for (int mt = 0; mt < 4; ++mt)
#pragma unroll
        for (int nt = 0; nt < 4; ++nt) {
            int col = n0 + wn * 64 + nt * 16 + lm;
#pragma unroll
            for (int r = 0; r < 4; ++r) {
                int row = m0 + wm * 64 + mt * 16 + rq * 4 + r;
                C[(size_t)row * ldc + col] = acc[mt][nt][r];
            }
        }
}

extern "C" void kernel_launch(void* const* d_in, const int* in_sizes, int n_in,
                              void* d_out, int out_size, void* d_ws, size_t ws_size,
                              hipStream_t stream) {
    const float* hs    = (const float*)d_in[0];
    const float* cosp  = (const float*)d_in[1];
    const float* sinp  = (const float*)d_in[2];
    const float* W_rkv = (const float*)d_in[3];
    const float* W_o   = (const float*)d_in[4];
    const float* td    = (const float*)d_in[5];
    const float* tf    = (const float*)d_in[6];
    const float* tm    = (const float*)d_in[7];
    float* out = (float*)d_out;

    char* w = (char*)d_ws;
    unsigned short* rP    = (unsigned short*)w;                   // 16 MiB
    unsigned short* kvP   = (unsigned short*)(w + 16777216);      // 16 MiB
    unsigned short* Ah    = (unsigned short*)(w + 33554432);      // 16 MiB
    unsigned short* Wrh   = (unsigned short*)(w + 50331648);      // 6 MiB
    unsigned short* Woh   = (unsigned short*)(w + 56623104);      // 2 MiB
    unsigned short* outH  = (unsigned short*)(w + 58720256);      // 16 MiB
    float*          Cb    = (float*)(w + 75497472);               // 256 KiB
    float*          Sb    = (float*)(w + 75759616);               // 256 KiB
    float*          a_ptr = (float*)(w + 76021760);

    k_avg_decay<<<1, 64, 0, stream>>>(td, a_ptr);

    k_split_mix<<<(M_TOTAL * HIDN / 4) / 256, 256, 0, stream>>>(hs, tm, Ah);
    k_split_w<<<(N_RKV * HIDN / 4) / 256, 256, 0, stream>>>(W_rkv, Wrh);
    k_split_w<<<(HIDN * HIDN / 4) / 256, 256, 0, stream>>>(W_o, Woh);

    dim3 g1(NH, M_TOTAL / 128);   // (16 heads, 64 chunks)
    k_gemm1_fused<<<g1, 192, 0, stream>>>(Ah, Wrh, cosp, sinp, a_ptr, rP, kvP, Cb);

    k_chunk_suffix<<<BATCH * NH, 64, 0, stream>>>(Cb, a_ptr, Sb);
    k_wkv2<<<BATCH * NH * NC, 256, 0, stream>>>(rP, kvP, Sb, a_ptr, tf, outH);

    dim3 g2(HIDN / 128, M_TOTAL / 128);
    k_mfma_gemm<<<g2, 256, 0, stream>>>(outH, HIDN, Woh, HIDN, out, HIDN);
}